// Round 10
// baseline (124.276 us; speedup 1.0000x reference)
//
#include <hip/hip_runtime.h>

typedef unsigned short u16;
typedef __attribute__((ext_vector_type(4))) float f4;
typedef __attribute__((ext_vector_type(4))) unsigned short us4;
typedef __attribute__((ext_vector_type(8))) unsigned short us8;
typedef __attribute__((ext_vector_type(8))) short s8v;
typedef __attribute__((ext_vector_type(4))) float f32x4;
typedef __attribute__((ext_vector_type(4))) unsigned int u4v;

#define DEVI __device__ __forceinline__

DEVI u16 f2bf(float f) {
  unsigned u = __float_as_uint(f);
  u = (u + 0x7FFFu + ((u >> 16) & 1u)) >> 16;
  return (u16)u;
}
DEVI float bf2f(u16 v) { return __uint_as_float(((unsigned)v) << 16); }
DEVI float siluf(float x) { return x / (1.f + __expf(-x)); }

// ---------------- fused converts (x, W_in, W_out, W_dt, W_x-padded) -------
__global__ void k_cvt_all(const float* __restrict__ x, const float* __restrict__ w1,
                          const float* __restrict__ wo, const float* __restrict__ wdt,
                          const float* __restrict__ wx,
                          u16* __restrict__ xb, u16* __restrict__ w1b,
                          u16* __restrict__ wob, u16* __restrict__ wdtb,
                          u16* __restrict__ wxb) {
  const int blk = blockIdx.x;
  const int tid = threadIdx.x;
  if (blk >= 7232) {  // W_x: 96x1024 -> 128x1024 zero-padded
    int i = (blk - 7232) * 256 + tid;
    int row = i >> 8;
    us4 o;
    if (row < 96) {
      f4 v = ((const f4*)wx)[i];
#pragma unroll
      for (int j = 0; j < 4; ++j) o[j] = f2bf(v[j]);
    } else {
      o[0] = 0; o[1] = 0; o[2] = 0; o[3] = 0;
    }
    ((us4*)wxb)[i] = o;
    return;
  }
  const float* src; u16* dst; int i;
  if (blk < 4096)      { src = x;   dst = xb;   i = blk * 256 + tid; }
  else if (blk < 6144) { src = w1;  dst = w1b;  i = (blk - 4096) * 256 + tid; }
  else if (blk < 7168) { src = wo;  dst = wob;  i = (blk - 6144) * 256 + tid; }
  else                 { src = wdt; dst = wdtb; i = (blk - 7168) * 256 + tid; }
  f4 v = ((const f4*)src)[i];
  us4 o;
#pragma unroll
  for (int j = 0; j < 4; ++j) o[j] = f2bf(v[j]);
  ((us4*)dst)[i] = o;
}

// ---------------- bf16 NT GEMM: 128x128 tile, BK=64, 8 waves (512 thr) -----
// Wave grid 2M x 4N; per-wave output 64x32 (acc 4x2 frags).
// LDS: A planes [2][128][32]bf16 @ 0,8K; B planes @ 16K,24K (32 KB total).
// EPI 0: fp32 store to C (+blockIdx.z*zstride for split-K parts)
// EPI 1: fp32 store to C, multiplied by silu(bf16 zsrc[rr*1024+cc])
// EPI 2: GEMM1 fused epilogue. nBase>=1024: z half -> ob2 (bf16, coalesced).
//        nBase<1024: conv(width3,per-batch-pad)+silu for interior rows 1..126
//        -> ob3 (xs); xc rows {0,1,126,127} -> ob1 (for the fixup kernel).
// EPI 3: bf16 store of softplus(v + bvec[cc]) + 1e-5 -> ob1 (dt)
// EPI 4: bf16 store to ob1 (+blockIdx.z*zstride), ldc stride (split-K parts)
template <int EPI>
__global__ __launch_bounds__(512, 2)
void k_gemm_bt(const u16* __restrict__ A, int lda,
               const u16* __restrict__ B, int ldb,
               float* __restrict__ C, int ldc, int nvalid,
               int K, int kchunk, size_t zstride, int lognx,
               const float* __restrict__ bvec,
               const u16* __restrict__ zsrc,
               u16* __restrict__ ob1, u16* __restrict__ ob2,
               const float* __restrict__ cw, u16* __restrict__ ob3) {
  __shared__ __align__(16) char smem[32768];
  const int tid = threadIdx.x;
  const int wave = tid >> 6, lane = tid & 63;

  // XCD-aware bijective swizzle (nwg % 8 == 0 for all call sites)
  const int nwg = gridDim.x * gridDim.y;
  int bid = blockIdx.y * gridDim.x + blockIdx.x;
  {
    const int cpx = nwg >> 3;
    bid = (bid & 7) * cpx + (bid >> 3);
  }
  const int mBase = (bid >> lognx) << 7;
  const int nBase = (bid & ((1 << lognx) - 1)) << 7;
  const int kbeg = blockIdx.z * kchunk;
  int kend = kbeg + kchunk; if (kend > K) kend = K;
  if (EPI == 4) ob1 += (size_t)blockIdx.z * zstride;
  else          C   += (size_t)blockIdx.z * zstride;

  const int wr = wave >> 2, wc = wave & 3;      // 2M x 4N wave grid
  const int row0 = tid >> 2, kg = tid & 3;      // 128 stage rows x 4 k-groups

  const u16* Ag = A + (size_t)(mBase + row0) * lda + kg * 8;
  const u16* Bg = B + (size_t)(nBase + row0) * ldb + kg * 8;
  char* ldsA0 = smem + wave * 1024;
  char* ldsA1 = smem + 8192 + wave * 1024;
  char* ldsB0 = smem + 16384 + wave * 1024;
  char* ldsB1 = smem + 24576 + wave * 1024;
  const u16* As = (const u16*)smem;
  const u16* Bs = (const u16*)(smem + 16384);

  const int fr = lane & 15, fk = (lane >> 4) << 3;
  const int aoff = ((wr << 6) + fr) * 32 + fk;  // within a 128x32 plane
  const int boff = ((wc << 5) + fr) * 32 + fk;

  f32x4 acc[4][2];
#pragma unroll
  for (int m = 0; m < 4; ++m)
#pragma unroll
    for (int n = 0; n < 2; ++n) acc[m][n] = {0.f, 0.f, 0.f, 0.f};

  for (int k0 = kbeg; k0 < kend; k0 += 64) {
    __syncthreads();
    __builtin_amdgcn_global_load_lds((const __attribute__((address_space(1))) void*)(Ag + k0),
                                     (__attribute__((address_space(3))) void*)(ldsA0), 16, 0, 0);
    __builtin_amdgcn_global_load_lds((const __attribute__((address_space(1))) void*)(Ag + k0 + 32),
                                     (__attribute__((address_space(3))) void*)(ldsA1), 16, 0, 0);
    __builtin_amdgcn_global_load_lds((const __attribute__((address_space(1))) void*)(Bg + k0),
                                     (__attribute__((address_space(3))) void*)(ldsB0), 16, 0, 0);
    __builtin_amdgcn_global_load_lds((const __attribute__((address_space(1))) void*)(Bg + k0 + 32),
                                     (__attribute__((address_space(3))) void*)(ldsB1), 16, 0, 0);
    __syncthreads();
#pragma unroll
    for (int kk = 0; kk < 2; ++kk) {
      const u16* Ap = As + (kk << 12);
      const u16* Bp = Bs + (kk << 12);
      s8v av[4], bv[2];
#pragma unroll
      for (int m = 0; m < 4; ++m) av[m] = *(const s8v*)(Ap + aoff + (m << 9));
#pragma unroll
      for (int n = 0; n < 2; ++n) bv[n] = *(const s8v*)(Bp + boff + (n << 9));
#pragma unroll
      for (int m = 0; m < 4; ++m)
#pragma unroll
        for (int n = 0; n < 2; ++n)
          acc[m][n] = __builtin_amdgcn_mfma_f32_16x16x32_bf16(av[m], bv[n], acc[m][n], 0, 0, 0);
    }
  }

  if (EPI == 2) {
    // stage full 128x128 bf16 tile once
    u16* ct = (u16*)smem;
    const int r16 = (lane >> 4) << 2;
    __syncthreads();
#pragma unroll
    for (int m = 0; m < 4; ++m)
#pragma unroll
      for (int n = 0; n < 2; ++n)
#pragma unroll
        for (int j = 0; j < 4; ++j)
          ct[((wr << 6) + (m << 4) + r16 + j) * 128 + (wc << 5) + (n << 4) + fr] =
              f2bf(acc[m][n][j]);
    __syncthreads();
    if (nBase >= 1024) {
      // z half: plain coalesced bf16 stores
      const int ncol = nBase - 1024;
#pragma unroll
      for (int it = 0; it < 4; ++it) {
        const int s = it * 512 + tid;
        const int tr = s >> 4, colq = (s & 15) << 3;
        *(us8*)(ob2 + ((size_t)(mBase + tr) << 10) + ncol + colq) =
            *(const us8*)(ct + tr * 128 + colq);
      }
    } else {
      // xc half: fused conv+silu (interior rows); xc rows {0,1,126,127} -> ob1
      const int ncol = nBase;
#pragma unroll
      for (int it = 0; it < 4; ++it) {
        const int s = it * 512 + tid;
        const int tr = s >> 4, colq = (s & 15) << 3;
        us8 curv = *(const us8*)(ct + tr * 128 + colq);
        if (tr < 2 || tr > 125)
          *(us8*)(ob1 + ((size_t)(mBase + tr) << 10) + ncol + colq) = curv;
        if (tr >= 1 && tr <= 126) {
          us8 lft = *(const us8*)(ct + (tr - 1) * 128 + colq);
          us8 rgt = *(const us8*)(ct + (tr + 1) * 128 + colq);
          const float* cwp = cw + (ncol + colq) * 3;
          us8 o;
#pragma unroll
          for (int j = 0; j < 8; ++j) {
            float xcv = bf2f(lft[j]) * cwp[j * 3] + bf2f(curv[j]) * cwp[j * 3 + 1] +
                        bf2f(rgt[j]) * cwp[j * 3 + 2];
            o[j] = f2bf(siluf(xcv));
          }
          *(us8*)(ob3 + ((size_t)(mBase + tr) << 10) + ncol + colq) = o;
        }
      }
    }
    return;
  }

  const int crow0 = mBase + (wr << 6) + ((lane >> 4) << 2);
  const int ccol0 = nBase + (wc << 5) + (lane & 15);
#pragma unroll
  for (int m = 0; m < 4; ++m) {
#pragma unroll
    for (int n = 0; n < 2; ++n) {
      const int cc = ccol0 + (n << 4);
      if (cc < nvalid) {
#pragma unroll
        for (int j = 0; j < 4; ++j) {
          const int rr = crow0 + (m << 4) + j;
          float v = acc[m][n][j];
          if (EPI == 0) {
            C[(size_t)rr * ldc + cc] = v;
          } else if (EPI == 1) {
            v *= siluf(bf2f(zsrc[((size_t)rr << 10) + cc]));
            C[(size_t)rr * ldc + cc] = v;
          } else if (EPI == 3) {
            float pre = v + bvec[cc];
            float dtv = (pre > 20.f ? pre : __logf(1.f + __expf(pre))) + 1e-5f;
            ob1[((size_t)rr << 10) + cc] = f2bf(dtv);
          } else {  // EPI == 4
            ob1[(size_t)rr * ldc + cc] = f2bf(v);
          }
        }
      }
    }
  }
}

// ---------------- conv fixup: rows t ≡ {0,127} mod 128 -------------------
__global__ void k_conv_fix(const u16* __restrict__ xcb, const float* __restrict__ conv_w,
                           u16* __restrict__ xsb) {
  const int k = blockIdx.x >> 1;                       // tile index 0..31
  const int bt = (k << 7) + ((blockIdx.x & 1) ? 127 : 0);
  const int t = bt & 2047;
  const int d = threadIdx.x << 2;
  auto ld = [&](int row) -> f4 {
    us4 v = *(const us4*)(xcb + ((size_t)row << 10) + d);
    f4 r;
#pragma unroll
    for (int j = 0; j < 4; ++j) r[j] = bf2f(v[j]);
    return r;
  };
  const f4 zero = {0.f, 0.f, 0.f, 0.f};
  f4 l = (t > 0) ? ld(bt - 1) : zero;
  f4 c = ld(bt);
  f4 r = (t < 2047) ? ld(bt + 1) : zero;
  const f4* cwq = (const f4*)(conv_w + d * 3);
  f4 c0 = cwq[0], c1 = cwq[1], c2 = cwq[2];
  const float w[12] = {c0[0], c0[1], c0[2], c0[3], c1[0], c1[1], c1[2], c1[3],
                       c2[0], c2[1], c2[2], c2[3]};
  us4 o;
#pragma unroll
  for (int j = 0; j < 4; ++j) {
    float xcv = l[j] * w[j * 3] + c[j] * w[j * 3 + 1] + r[j] * w[j * 3 + 2];
    o[j] = f2bf(siluf(xcv));
  }
  *(us4*)(xsb + ((size_t)bt << 10) + d) = o;
}

// ---------------- split-K reduce (8 bf16 parts) -> bf16 x_dbl ------------
__global__ void k_red8(const u16* __restrict__ parts, u16* __restrict__ xdblb) {
  const int i = blockIdx.x * 256 + threadIdx.x;  // us4 quads over 4096*96/4
  f4 s = {0.f, 0.f, 0.f, 0.f};
#pragma unroll
  for (int z = 0; z < 8; ++z) {
    us4 v = ((const us4*)(parts + (size_t)z * 393216))[i];
#pragma unroll
    for (int j = 0; j < 4; ++j) s[j] += bf2f(v[j]);
  }
  us4 o;
#pragma unroll
  for (int j = 0; j < 4; ++j) o[j] = f2bf(s[j]);
  ((us4*)xdblb)[i] = o;
}

// ---------------- chunked scan: L=32, NC=64, layout [b][c][d][n] ----------
// pass A: per-chunk prod(A) and local end state, packed bf16x2 in u32
__global__ void k_scanA(const u16* __restrict__ dtb, const u16* __restrict__ xsb,
                        const u16* __restrict__ xdblb, const float* __restrict__ A_log,
                        unsigned* __restrict__ PS) {
  __shared__ float bxs[32][16];
  const int tid = threadIdx.x;
  const int d = (blockIdx.x << 8) + tid;
  const int c = blockIdx.y;
  const int b = blockIdx.z;
  const int btBase = (b << 11) + (c << 5);
  for (int i = tid; i < 512; i += 256) {
    bxs[i >> 4][i & 15] = bf2f(xdblb[(size_t)(btBase + (i >> 4)) * 96 + 64 + (i & 15)]);
  }
  float a[16];
  {
    const f4* al = (const f4*)(A_log + d * 16);
#pragma unroll
    for (int q = 0; q < 4; ++q) {
      f4 v = al[q];
#pragma unroll
      for (int j = 0; j < 4; ++j) a[q * 4 + j] = -__expf(v[j]);
    }
  }
  bool uni = true;
#pragma unroll
  for (int n = 1; n < 16; ++n) uni = uni && (a[n] == a[0]);
  __syncthreads();
  float P[16], S[16];
#pragma unroll
  for (int n = 0; n < 16; ++n) { P[n] = 1.f; S[n] = 0.f; }
  if (uni) {
    const float a0 = a[0];
    float Pu = 1.f;
    for (int tau = 0; tau < 32; ++tau) {
      const size_t bt = btBase + tau;
      const float dt = bf2f(dtb[(bt << 10) + d]);
      const float dx = dt * bf2f(xsb[(bt << 10) + d]);
      const float Av = __expf(a0 * dt);
      Pu *= Av;
#pragma unroll
      for (int n = 0; n < 16; ++n) S[n] = fmaf(Av, S[n], bxs[tau][n] * dx);
    }
#pragma unroll
    for (int n = 0; n < 16; ++n) P[n] = Pu;
  } else {
    for (int tau = 0; tau < 32; ++tau) {
      const size_t bt = btBase + tau;
      const float dt = bf2f(dtb[(bt << 10) + d]);
      const float dx = dt * bf2f(xsb[(bt << 10) + d]);
#pragma unroll
      for (int n = 0; n < 16; ++n) {
        const float Av = __expf(a[n] * dt);
        P[n] *= Av;
        S[n] = fmaf(Av, S[n], bxs[tau][n] * dx);
      }
    }
  }
  const size_t base = (size_t)(((b << 6) + c) * 1024 + d) << 4;
#pragma unroll
  for (int q = 0; q < 4; ++q) {
    u4v pk;
#pragma unroll
    for (int j = 0; j < 4; ++j) {
      pk[j] = (unsigned)f2bf(P[q * 4 + j]) | ((unsigned)f2bf(S[q * 4 + j]) << 16);
    }
    *(u4v*)(PS + base + q * 4) = pk;
  }
}

// pass B: sequential combine of 64 chunk summaries -> chunk init states (bf16)
__global__ void k_scanB(const unsigned* __restrict__ PS, u16* __restrict__ SI) {
  const int i = (blockIdx.x << 8) + threadIdx.x;  // 32768
  const int n = i & 15;
  const int dd = (i >> 4) & 1023;
  const int b = i >> 14;
  float s = 0.f;
  for (int c = 0; c < 64; ++c) {
    const size_t idx = ((size_t)(((b << 6) + c) * 1024 + dd) << 4) + n;
    const unsigned w = PS[idx];
    SI[idx] = f2bf(s);
    s = fmaf(bf2f((u16)(w & 0xFFFF)), s, bf2f((u16)(w >> 16)));
  }
}

// pass C: replay chunk with known init state; emit y (bf16)
__global__ void k_scanC(const u16* __restrict__ dtb, const u16* __restrict__ xsb,
                        const u16* __restrict__ xdblb, const float* __restrict__ A_log,
                        const u16* __restrict__ SI, const float* __restrict__ W_C,
                        const float* __restrict__ D_param, u16* __restrict__ yb) {
  __shared__ float bxs[32][32];  // [tau][0:16)=B, [16:32)=C
  const int tid = threadIdx.x;
  const int d = (blockIdx.x << 8) + tid;
  const int c = blockIdx.y;
  const int b = blockIdx.z;
  const int btBase = (b << 11) + (c << 5);
  for (int i = tid; i < 1024; i += 256) {
    bxs[i >> 5][i & 31] = bf2f(xdblb[(size_t)(btBase + (i >> 5)) * 96 + 64 + (i & 31)]);
  }
  float a[16], wc[16];
  {
    const f4* al = (const f4*)(A_log + d * 16);
    const f4* wcp = (const f4*)(W_C + d * 16);
#pragma unroll
    for (int q = 0; q < 4; ++q) {
      f4 v = al[q], u = wcp[q];
#pragma unroll
      for (int j = 0; j < 4; ++j) { a[q * 4 + j] = -__expf(v[j]); wc[q * 4 + j] = u[j]; }
    }
  }
  bool uni = true;
#pragma unroll
  for (int n = 1; n < 16; ++n) uni = uni && (a[n] == a[0]);
  const float Dp = D_param[d];
  float s[16];
  const size_t base = (size_t)(((b << 6) + c) * 1024 + d) << 4;
#pragma unroll
  for (int q = 0; q < 4; ++q) {
    us4 v = *(const us4*)(SI + base + q * 4);
#pragma unroll
    for (int j = 0; j < 4; ++j) s[q * 4 + j] = bf2f(v[j]);
  }
  __syncthreads();
  if (uni) {
    const float a0 = a[0];
    for (int tau = 0; tau < 32; ++tau) {
      const size_t bt = btBase + tau;
      const float dt = bf2f(dtb[(bt << 10) + d]);
      const float xs = bf2f(xsb[(bt << 10) + d]);
      const float dx = dt * xs;
      const float Av = __expf(a0 * dt);
      float ssum = 0.f, cp = 0.f;
#pragma unroll
      for (int n = 0; n < 16; ++n) {
        s[n] = fmaf(Av, s[n], bxs[tau][n] * dx);
        ssum += s[n];
        cp = fmaf(bxs[tau][16 + n], wc[n], cp);
      }
      const float y = fmaf(cp, ssum, Dp * xs);
      yb[(bt << 10) + d] = f2bf(y);
    }
  } else {
    for (int tau = 0; tau < 32; ++tau) {
      const size_t bt = btBase + tau;
      const float dt = bf2f(dtb[(bt << 10) + d]);
      const float xs = bf2f(xsb[(bt << 10) + d]);
      const float dx = dt * xs;
      float ssum = 0.f, cp = 0.f;
#pragma unroll
      for (int n = 0; n < 16; ++n) {
        const float Av = __expf(a[n] * dt);
        s[n] = fmaf(Av, s[n], bxs[tau][n] * dx);
        ssum += s[n];
        cp = fmaf(bxs[tau][16 + n], wc[n], cp);
      }
      const float y = fmaf(cp, ssum, Dp * xs);
      yb[(bt << 10) + d] = f2bf(y);
    }
  }
}

extern "C" void kernel_launch(void* const* d_in, const int* in_sizes, int n_in,
                              void* d_out, int out_size, void* d_ws, size_t ws_size,
                              hipStream_t stream) {
  const float* x     = (const float*)d_in[0];
  const float* W_in  = (const float*)d_in[1];
  const float* convw = (const float*)d_in[2];
  const float* W_x   = (const float*)d_in[3];
  const float* W_dt  = (const float*)d_in[4];
  const float* b_dt  = (const float*)d_in[5];
  const float* A_log = (const float*)d_in[6];
  const float* D_par = (const float*)d_in[7];
  const float* W_C   = (const float*)d_in[8];
  const float* W_out = (const float*)d_in[9];
  float* out = (float*)d_out;
  (void)in_sizes; (void)n_in; (void)out_size; (void)ws_size;

  char* w = (char*)d_ws;
  auto take = [&](size_t bytes) { char* p = w; w += (bytes + 255) & ~(size_t)255; return p; };
  u16* xb     = (u16*)take(8388608);     // x bf16 [4096][1024]
  u16* w1b    = (u16*)take(4194304);     // W_in bf16 [2048][1024]
  u16* wxb    = (u16*)take(262144);      // W_x bf16 padded [128][1024]
  u16* wob    = (u16*)take(2097152);     // W_out bf16 [1024][1024]
  u16* wdtb   = (u16*)take(131072);      // W_dt bf16 [1024][64]
  u16* xdblb  = (u16*)take(786432);      // x_dbl bf16 [4096][96]
  u16* yb     = (u16*)take(8388608);     // y bf16 [4096][1024]
  u16* xsb    = (u16*)take(8388608);     // xs bf16 [4096][1024]
  u16* xcb    = (u16*)take(8388608);     // xc bf16 (boundary rows only used)
  u16* zb     = (u16*)take(8388608);     // z bf16 [4096][1024]
  u16* dtb    = (u16*)take(8388608);     // dt bf16 (post-softplus) [4096][1024]
  u16* xdblp  = (u16*)take(6291456);     // split-K bf16 parts [8][4096][96]
  unsigned* PS= (unsigned*)take(8388608);// packed (P,S) bf16x2 [b][c=64][d][n]
  u16* SI     = (u16*)take(4194304);     // chunk init states bf16

  // converts (fused)
  k_cvt_all<<<7360, 256, 0, stream>>>(x, W_in, W_out, W_dt, W_x,
                                      xb, w1b, wob, wdtb, wxb);
  // GEMM1: x @ W_in^T; epilogue: z->zb, conv+silu interior -> xsb, xc edges -> xcb
  dim3 g1(16, 32, 1);
  k_gemm_bt<2><<<g1, 512, 0, stream>>>(xb, 1024, w1b, 1024, nullptr, 0, 2048,
                                       1024, 1024, 0, 4, nullptr, nullptr, xcb, zb,
                                       convw, xsb);
  // conv fixup for rows t ≡ {0,127} mod 128
  k_conv_fix<<<64, 256, 0, stream>>>(xcb, convw, xsb);
  // GEMM2: x_dbl = xs @ W_x^T (deterministic split-K=8, bf16 parts)
  dim3 g2(1, 32, 8);
  k_gemm_bt<4><<<g2, 512, 0, stream>>>(xsb, 1024, wxb, 1024, nullptr, 96, 96,
                                       1024, 128, 393216, 0, nullptr, nullptr, xdblp, nullptr,
                                       nullptr, nullptr);
  k_red8<<<384, 256, 0, stream>>>(xdblp, xdblb);
  // dt GEMM (K=64) with fused softplus+bias -> bf16 dt
  dim3 g4(8, 32, 1);
  k_gemm_bt<3><<<g4, 512, 0, stream>>>(xdblb, 96, wdtb, 64, nullptr, 0, 1024,
                                       64, 64, 0, 3, b_dt, nullptr, dtb, nullptr,
                                       nullptr, nullptr);
  // chunked scan (L=32, NC=64), uniform-A fast path
  dim3 gs(4, 64, 2);
  k_scanA<<<gs, 256, 0, stream>>>(dtb, xsb, xdblb, A_log, PS);
  k_scanB<<<128, 256, 0, stream>>>(PS, SI);
  k_scanC<<<gs, 256, 0, stream>>>(dtb, xsb, xdblb, A_log, SI, W_C, D_par, yb);
  // GEMM3: out = (y @ W_out^T) * silu(z)  (z bf16)
  dim3 g3(8, 32, 1);
  k_gemm_bt<1><<<g3, 512, 0, stream>>>(yb, 1024, wob, 1024, out, 1024, 1024,
                                       1024, 1024, 0, 3, nullptr, zb, nullptr, nullptr,
                                       nullptr, nullptr);
}

// Round 11
// 118.953 us; speedup vs baseline: 1.0447x; 1.0447x over previous
//
#include <hip/hip_runtime.h>

typedef unsigned short u16;
typedef __attribute__((ext_vector_type(4))) float f4;
typedef __attribute__((ext_vector_type(4))) unsigned short us4;
typedef __attribute__((ext_vector_type(8))) unsigned short us8;
typedef __attribute__((ext_vector_type(8))) short s8v;
typedef __attribute__((ext_vector_type(4))) float f32x4;
typedef __attribute__((ext_vector_type(4))) unsigned int u4v;

#define DEVI __device__ __forceinline__

DEVI u16 f2bf(float f) {
  unsigned u = __float_as_uint(f);
  u = (u + 0x7FFFu + ((u >> 16) & 1u)) >> 16;
  return (u16)u;
}
DEVI float bf2f(u16 v) { return __uint_as_float(((unsigned)v) << 16); }
DEVI float siluf(float x) { return x / (1.f + __expf(-x)); }

// ---------------- fused converts (x, W_in, W_out, W_dt, W_x-padded) -------
__global__ void k_cvt_all(const float* __restrict__ x, const float* __restrict__ w1,
                          const float* __restrict__ wo, const float* __restrict__ wdt,
                          const float* __restrict__ wx,
                          u16* __restrict__ xb, u16* __restrict__ w1b,
                          u16* __restrict__ wob, u16* __restrict__ wdtb,
                          u16* __restrict__ wxb) {
  const int blk = blockIdx.x;
  const int tid = threadIdx.x;
  if (blk >= 7232) {  // W_x: 96x1024 -> 128x1024 zero-padded
    int i = (blk - 7232) * 256 + tid;
    int row = i >> 8;
    us4 o;
    if (row < 96) {
      f4 v = ((const f4*)wx)[i];
#pragma unroll
      for (int j = 0; j < 4; ++j) o[j] = f2bf(v[j]);
    } else {
      o[0] = 0; o[1] = 0; o[2] = 0; o[3] = 0;
    }
    ((us4*)wxb)[i] = o;
    return;
  }
  const float* src; u16* dst; int i;
  if (blk < 4096)      { src = x;   dst = xb;   i = blk * 256 + tid; }
  else if (blk < 6144) { src = w1;  dst = w1b;  i = (blk - 4096) * 256 + tid; }
  else if (blk < 7168) { src = wo;  dst = wob;  i = (blk - 6144) * 256 + tid; }
  else                 { src = wdt; dst = wdtb; i = (blk - 7168) * 256 + tid; }
  f4 v = ((const f4*)src)[i];
  us4 o;
#pragma unroll
  for (int j = 0; j < 4; ++j) o[j] = f2bf(v[j]);
  ((us4*)dst)[i] = o;
}

// ---------------- bf16 NT GEMM: 128x128 tile, BK=64, 8 waves (512 thr) -----
// Wave grid 2M x 4N; per-wave output 64x32 (acc 4x2 frags).
// LDS: A planes [2][128][32]bf16 @ 0,8K; B planes @ 16K,24K (32 KB total).
// EPI 0: fp32 store to C (+blockIdx.z*zstride for split-K parts)
// EPI 1: fp32 store to C, multiplied by silu(bf16 zsrc[rr*1024+cc])
// EPI 2: bf16 full-tile LDS-staged coalesced split store: nBase<1024->ob1 else ob2
// EPI 3: bf16 store of softplus(v + bvec[cc]) + 1e-5 -> ob1 (dt)
// EPI 4: bf16 store to ob1 (+blockIdx.z*zstride), ldc stride (split-K parts)
template <int EPI>
__global__ __launch_bounds__(512, 2)
void k_gemm_bt(const u16* __restrict__ A, int lda,
               const u16* __restrict__ B, int ldb,
               float* __restrict__ C, int ldc, int nvalid,
               int K, int kchunk, size_t zstride, int lognx,
               const float* __restrict__ bvec,
               const u16* __restrict__ zsrc,
               u16* __restrict__ ob1, u16* __restrict__ ob2) {
  __shared__ __align__(16) char smem[32768];
  const int tid = threadIdx.x;
  const int wave = tid >> 6, lane = tid & 63;

  // XCD-aware bijective swizzle (nwg % 8 == 0 for all call sites)
  const int nwg = gridDim.x * gridDim.y;
  int bid = blockIdx.y * gridDim.x + blockIdx.x;
  {
    const int cpx = nwg >> 3;
    bid = (bid & 7) * cpx + (bid >> 3);
  }
  const int mBase = (bid >> lognx) << 7;
  const int nBase = (bid & ((1 << lognx) - 1)) << 7;
  const int kbeg = blockIdx.z * kchunk;
  int kend = kbeg + kchunk; if (kend > K) kend = K;
  if (EPI == 4) ob1 += (size_t)blockIdx.z * zstride;
  else          C   += (size_t)blockIdx.z * zstride;

  const int wr = wave >> 2, wc = wave & 3;      // 2M x 4N wave grid
  const int row0 = tid >> 2, kg = tid & 3;      // 128 stage rows x 4 k-groups

  const u16* Ag = A + (size_t)(mBase + row0) * lda + kg * 8;
  const u16* Bg = B + (size_t)(nBase + row0) * ldb + kg * 8;
  char* ldsA0 = smem + wave * 1024;
  char* ldsA1 = smem + 8192 + wave * 1024;
  char* ldsB0 = smem + 16384 + wave * 1024;
  char* ldsB1 = smem + 24576 + wave * 1024;
  const u16* As = (const u16*)smem;
  const u16* Bs = (const u16*)(smem + 16384);

  const int fr = lane & 15, fk = (lane >> 4) << 3;
  const int aoff = ((wr << 6) + fr) * 32 + fk;  // within a 128x32 plane
  const int boff = ((wc << 5) + fr) * 32 + fk;

  f32x4 acc[4][2];
#pragma unroll
  for (int m = 0; m < 4; ++m)
#pragma unroll
    for (int n = 0; n < 2; ++n) acc[m][n] = {0.f, 0.f, 0.f, 0.f};

  for (int k0 = kbeg; k0 < kend; k0 += 64) {
    __syncthreads();
    __builtin_amdgcn_global_load_lds((const __attribute__((address_space(1))) void*)(Ag + k0),
                                     (__attribute__((address_space(3))) void*)(ldsA0), 16, 0, 0);
    __builtin_amdgcn_global_load_lds((const __attribute__((address_space(1))) void*)(Ag + k0 + 32),
                                     (__attribute__((address_space(3))) void*)(ldsA1), 16, 0, 0);
    __builtin_amdgcn_global_load_lds((const __attribute__((address_space(1))) void*)(Bg + k0),
                                     (__attribute__((address_space(3))) void*)(ldsB0), 16, 0, 0);
    __builtin_amdgcn_global_load_lds((const __attribute__((address_space(1))) void*)(Bg + k0 + 32),
                                     (__attribute__((address_space(3))) void*)(ldsB1), 16, 0, 0);
    __syncthreads();
#pragma unroll
    for (int kk = 0; kk < 2; ++kk) {
      const u16* Ap = As + (kk << 12);
      const u16* Bp = Bs + (kk << 12);
      s8v av[4], bv[2];
#pragma unroll
      for (int m = 0; m < 4; ++m) av[m] = *(const s8v*)(Ap + aoff + (m << 9));
#pragma unroll
      for (int n = 0; n < 2; ++n) bv[n] = *(const s8v*)(Bp + boff + (n << 9));
#pragma unroll
      for (int m = 0; m < 4; ++m)
#pragma unroll
        for (int n = 0; n < 2; ++n)
          acc[m][n] = __builtin_amdgcn_mfma_f32_16x16x32_bf16(av[m], bv[n], acc[m][n], 0, 0, 0);
    }
  }

  if (EPI == 2) {
    // full 128x128 bf16 tile staged once, then coalesced us8 stores
    u16* ct = (u16*)smem;
    const int r16 = (lane >> 4) << 2;
    __syncthreads();
#pragma unroll
    for (int m = 0; m < 4; ++m)
#pragma unroll
      for (int n = 0; n < 2; ++n)
#pragma unroll
        for (int j = 0; j < 4; ++j)
          ct[((wr << 6) + (m << 4) + r16 + j) * 128 + (wc << 5) + (n << 4) + fr] =
              f2bf(acc[m][n][j]);
    __syncthreads();
    u16* dst = (nBase < 1024) ? ob1 : ob2;
    const int ncol = nBase & 1023;
#pragma unroll
    for (int it = 0; it < 4; ++it) {
      const int s = it * 512 + tid;         // 2048 us8 slots
      const int tr = s >> 4, colq = (s & 15) << 3;
      *(us8*)(dst + ((size_t)(mBase + tr) << 10) + ncol + colq) =
          *(const us8*)(ct + tr * 128 + colq);
    }
    return;
  }

  const int crow0 = mBase + (wr << 6) + ((lane >> 4) << 2);
  const int ccol0 = nBase + (wc << 5) + (lane & 15);
#pragma unroll
  for (int m = 0; m < 4; ++m) {
#pragma unroll
    for (int n = 0; n < 2; ++n) {
      const int cc = ccol0 + (n << 4);
      if (cc < nvalid) {
#pragma unroll
        for (int j = 0; j < 4; ++j) {
          const int rr = crow0 + (m << 4) + j;
          float v = acc[m][n][j];
          if (EPI == 0) {
            C[(size_t)rr * ldc + cc] = v;
          } else if (EPI == 1) {
            v *= siluf(bf2f(zsrc[((size_t)rr << 10) + cc]));
            C[(size_t)rr * ldc + cc] = v;
          } else if (EPI == 3) {
            float pre = v + bvec[cc];
            float dtv = (pre > 20.f ? pre : __logf(1.f + __expf(pre))) + 1e-5f;
            ob1[((size_t)rr << 10) + cc] = f2bf(dtv);
          } else {  // EPI == 4
            ob1[(size_t)rr * ldc + cc] = f2bf(v);
          }
        }
      }
    }
  }
}

// ---------------- split-K reduce (8 bf16 parts) -> bf16 x_dbl ------------
__global__ void k_red8(const u16* __restrict__ parts, u16* __restrict__ xdblb) {
  const int i = blockIdx.x * 256 + threadIdx.x;  // us4 quads over 4096*96/4
  f4 s = {0.f, 0.f, 0.f, 0.f};
#pragma unroll
  for (int z = 0; z < 8; ++z) {
    us4 v = ((const us4*)(parts + (size_t)z * 393216))[i];
#pragma unroll
    for (int j = 0; j < 4; ++j) s[j] += bf2f(v[j]);
  }
  us4 o;
#pragma unroll
  for (int j = 0; j < 4; ++j) o[j] = f2bf(s[j]);
  ((us4*)xdblb)[i] = o;
}

// ---------------- conv(width3) + silu, rolling window, bf16 in/out -------
__global__ void k_conv2(const u16* __restrict__ xcb, const float* __restrict__ conv_w,
                        u16* __restrict__ xsb) {
  const int b = blockIdx.x >> 8;
  const int t0 = (blockIdx.x & 255) << 3;
  const int d = threadIdx.x << 2;
  const u16* base = xcb + ((size_t)b * 2048 << 10) + d;
  const f4* cw = (const f4*)(conv_w + d * 3);
  f4 c0 = cw[0], c1 = cw[1], c2 = cw[2];
  const float w[12] = {c0[0], c0[1], c0[2], c0[3], c1[0], c1[1], c1[2], c1[3],
                       c2[0], c2[1], c2[2], c2[3]};
  const f4 zero = {0.f, 0.f, 0.f, 0.f};
  auto ld = [&](int t) -> f4 {
    us4 v = *(const us4*)(base + ((size_t)t << 10));
    f4 r;
#pragma unroll
    for (int j = 0; j < 4; ++j) r[j] = bf2f(v[j]);
    return r;
  };
  f4 prev = (t0 == 0) ? zero : ld(t0 - 1);
  f4 cur = ld(t0);
#pragma unroll
  for (int i = 0; i < 8; ++i) {
    const int t = t0 + i;
    f4 nxt = (t == 2047) ? zero : ld(t + 1);
    us4 xbv;
#pragma unroll
    for (int j = 0; j < 4; ++j) {
      float xc = prev[j] * w[j * 3] + cur[j] * w[j * 3 + 1] + nxt[j] * w[j * 3 + 2];
      xbv[j] = f2bf(siluf(xc));
    }
    *(us4*)(xsb + ((size_t)(b * 2048 + t) << 10) + d) = xbv;
    prev = cur; cur = nxt;
  }
}

// ---------------- chunked scan: L=32, NC=64, layout [b][c][d][n] ----------
// pass A: per-chunk prod(A) and local end state, packed bf16x2 in u32.
// dt/xs slabs staged into LDS with us8 vector loads (Common-mistake #2 fix).
__global__ void k_scanA(const u16* __restrict__ dtb, const u16* __restrict__ xsb,
                        const u16* __restrict__ xdblb, const float* __restrict__ A_log,
                        unsigned* __restrict__ PS) {
  __shared__ float bxs[32][16];
  __shared__ __align__(16) u16 dts[32][256];
  __shared__ __align__(16) u16 xss[32][256];
  const int tid = threadIdx.x;
  const int d0 = blockIdx.x << 8;
  const int d = d0 + tid;
  const int c = blockIdx.y;
  const int b = blockIdx.z;
  const int btBase = (b << 11) + (c << 5);
  // slab loads: 32 rows x 256 cols bf16, us8 16B chunks (1024 total, 4/thread)
  {
    const u16* dtp = dtb + ((size_t)btBase << 10) + d0;
    const u16* xsp = xsb + ((size_t)btBase << 10) + d0;
#pragma unroll
    for (int k = 0; k < 4; ++k) {
      const int i = k * 256 + tid;
      const int row = i >> 5, c8 = (i & 31) << 3;
      *(us8*)&dts[row][c8] = *(const us8*)(dtp + ((size_t)row << 10) + c8);
      *(us8*)&xss[row][c8] = *(const us8*)(xsp + ((size_t)row << 10) + c8);
    }
  }
  for (int i = tid; i < 512; i += 256) {
    bxs[i >> 4][i & 15] = bf2f(xdblb[(size_t)(btBase + (i >> 4)) * 96 + 64 + (i & 15)]);
  }
  float a[16];
  {
    const f4* al = (const f4*)(A_log + d * 16);
#pragma unroll
    for (int q = 0; q < 4; ++q) {
      f4 v = al[q];
#pragma unroll
      for (int j = 0; j < 4; ++j) a[q * 4 + j] = -__expf(v[j]);
    }
  }
  bool uni = true;
#pragma unroll
  for (int n = 1; n < 16; ++n) uni = uni && (a[n] == a[0]);
  __syncthreads();
  float P[16], S[16];
#pragma unroll
  for (int n = 0; n < 16; ++n) { P[n] = 1.f; S[n] = 0.f; }
  if (uni) {
    const float a0 = a[0];
    float Pu = 1.f;
#pragma unroll
    for (int tau = 0; tau < 32; ++tau) {
      const float dt = bf2f(dts[tau][tid]);
      const float dx = dt * bf2f(xss[tau][tid]);
      const float Av = __expf(a0 * dt);
      Pu *= Av;
#pragma unroll
      for (int n = 0; n < 16; ++n) S[n] = fmaf(Av, S[n], bxs[tau][n] * dx);
    }
#pragma unroll
    for (int n = 0; n < 16; ++n) P[n] = Pu;
  } else {
#pragma unroll
    for (int tau = 0; tau < 32; ++tau) {
      const float dt = bf2f(dts[tau][tid]);
      const float dx = dt * bf2f(xss[tau][tid]);
#pragma unroll
      for (int n = 0; n < 16; ++n) {
        const float Av = __expf(a[n] * dt);
        P[n] *= Av;
        S[n] = fmaf(Av, S[n], bxs[tau][n] * dx);
      }
    }
  }
  const size_t base = (size_t)(((b << 6) + c) * 1024 + d) << 4;
#pragma unroll
  for (int q = 0; q < 4; ++q) {
    u4v pk;
#pragma unroll
    for (int j = 0; j < 4; ++j) {
      pk[j] = (unsigned)f2bf(P[q * 4 + j]) | ((unsigned)f2bf(S[q * 4 + j]) << 16);
    }
    *(u4v*)(PS + base + q * 4) = pk;
  }
}

// pass B: sequential combine of 64 chunk summaries -> chunk init states (bf16)
__global__ void k_scanB(const unsigned* __restrict__ PS, u16* __restrict__ SI) {
  const int i = (blockIdx.x << 8) + threadIdx.x;  // 32768
  const int n = i & 15;
  const int dd = (i >> 4) & 1023;
  const int b = i >> 14;
  float s = 0.f;
  for (int c = 0; c < 64; ++c) {
    const size_t idx = ((size_t)(((b << 6) + c) * 1024 + dd) << 4) + n;
    const unsigned w = PS[idx];
    SI[idx] = f2bf(s);
    s = fmaf(bf2f((u16)(w & 0xFFFF)), s, bf2f((u16)(w >> 16)));
  }
}

// pass C: replay chunk with known init state; emit y (bf16) via LDS slab
__global__ void k_scanC(const u16* __restrict__ dtb, const u16* __restrict__ xsb,
                        const u16* __restrict__ xdblb, const float* __restrict__ A_log,
                        const u16* __restrict__ SI, const float* __restrict__ W_C,
                        const float* __restrict__ D_param, u16* __restrict__ yb) {
  __shared__ float bxs[32][32];  // [tau][0:16)=B, [16:32)=C
  __shared__ __align__(16) u16 dts[32][256];
  __shared__ __align__(16) u16 xss[32][256];
  __shared__ __align__(16) u16 ys[32][256];
  const int tid = threadIdx.x;
  const int d0 = blockIdx.x << 8;
  const int d = d0 + tid;
  const int c = blockIdx.y;
  const int b = blockIdx.z;
  const int btBase = (b << 11) + (c << 5);
  {
    const u16* dtp = dtb + ((size_t)btBase << 10) + d0;
    const u16* xsp = xsb + ((size_t)btBase << 10) + d0;
#pragma unroll
    for (int k = 0; k < 4; ++k) {
      const int i = k * 256 + tid;
      const int row = i >> 5, c8 = (i & 31) << 3;
      *(us8*)&dts[row][c8] = *(const us8*)(dtp + ((size_t)row << 10) + c8);
      *(us8*)&xss[row][c8] = *(const us8*)(xsp + ((size_t)row << 10) + c8);
    }
  }
  for (int i = tid; i < 1024; i += 256) {
    bxs[i >> 5][i & 31] = bf2f(xdblb[(size_t)(btBase + (i >> 5)) * 96 + 64 + (i & 31)]);
  }
  float a[16], wc[16];
  {
    const f4* al = (const f4*)(A_log + d * 16);
    const f4* wcp = (const f4*)(W_C + d * 16);
#pragma unroll
    for (int q = 0; q < 4; ++q) {
      f4 v = al[q], u = wcp[q];
#pragma unroll
      for (int j = 0; j < 4; ++j) { a[q * 4 + j] = -__expf(v[j]); wc[q * 4 + j] = u[j]; }
    }
  }
  bool uni = true;
#pragma unroll
  for (int n = 1; n < 16; ++n) uni = uni && (a[n] == a[0]);
  const float Dp = D_param[d];
  float s[16];
  const size_t base = (size_t)(((b << 6) + c) * 1024 + d) << 4;
#pragma unroll
  for (int q = 0; q < 4; ++q) {
    us4 v = *(const us4*)(SI + base + q * 4);
#pragma unroll
    for (int j = 0; j < 4; ++j) s[q * 4 + j] = bf2f(v[j]);
  }
  __syncthreads();
  if (uni) {
    const float a0 = a[0];
#pragma unroll
    for (int tau = 0; tau < 32; ++tau) {
      const float dt = bf2f(dts[tau][tid]);
      const float xs = bf2f(xss[tau][tid]);
      const float dx = dt * xs;
      const float Av = __expf(a0 * dt);
      float ssum = 0.f, cp = 0.f;
#pragma unroll
      for (int n = 0; n < 16; ++n) {
        s[n] = fmaf(Av, s[n], bxs[tau][n] * dx);
        ssum += s[n];
        cp = fmaf(bxs[tau][16 + n], wc[n], cp);
      }
      ys[tau][tid] = f2bf(fmaf(cp, ssum, Dp * xs));
    }
  } else {
#pragma unroll
    for (int tau = 0; tau < 32; ++tau) {
      const float dt = bf2f(dts[tau][tid]);
      const float xs = bf2f(xss[tau][tid]);
      const float dx = dt * xs;
      float ssum = 0.f, cp = 0.f;
#pragma unroll
      for (int n = 0; n < 16; ++n) {
        const float Av = __expf(a[n] * dt);
        s[n] = fmaf(Av, s[n], bxs[tau][n] * dx);
        ssum += s[n];
        cp = fmaf(bxs[tau][16 + n], wc[n], cp);
      }
      ys[tau][tid] = f2bf(fmaf(cp, ssum, Dp * xs));
    }
  }
  __syncthreads();
  // vectorized y flush: 16B per store
  {
    u16* yp = yb + ((size_t)btBase << 10) + d0;
#pragma unroll
    for (int k = 0; k < 4; ++k) {
      const int i = k * 256 + tid;
      const int row = i >> 5, c8 = (i & 31) << 3;
      *(us8*)(yp + ((size_t)row << 10) + c8) = *(const us8*)&ys[row][c8];
    }
  }
}

extern "C" void kernel_launch(void* const* d_in, const int* in_sizes, int n_in,
                              void* d_out, int out_size, void* d_ws, size_t ws_size,
                              hipStream_t stream) {
  const float* x     = (const float*)d_in[0];
  const float* W_in  = (const float*)d_in[1];
  const float* convw = (const float*)d_in[2];
  const float* W_x   = (const float*)d_in[3];
  const float* W_dt  = (const float*)d_in[4];
  const float* b_dt  = (const float*)d_in[5];
  const float* A_log = (const float*)d_in[6];
  const float* D_par = (const float*)d_in[7];
  const float* W_C   = (const float*)d_in[8];
  const float* W_out = (const float*)d_in[9];
  float* out = (float*)d_out;
  (void)in_sizes; (void)n_in; (void)out_size; (void)ws_size;

  char* w = (char*)d_ws;
  auto take = [&](size_t bytes) { char* p = w; w += (bytes + 255) & ~(size_t)255; return p; };
  u16* xb     = (u16*)take(8388608);     // x bf16 [4096][1024]
  u16* w1b    = (u16*)take(4194304);     // W_in bf16 [2048][1024]
  u16* wxb    = (u16*)take(262144);      // W_x bf16 padded [128][1024]
  u16* wob    = (u16*)take(2097152);     // W_out bf16 [1024][1024]
  u16* wdtb   = (u16*)take(131072);      // W_dt bf16 [1024][64]
  u16* xdblb  = (u16*)take(786432);      // x_dbl bf16 [4096][96]
  u16* yb     = (u16*)take(8388608);     // y bf16 [4096][1024]
  u16* xsb    = (u16*)take(8388608);     // xs bf16 [4096][1024]
  u16* xcb    = (u16*)take(8388608);     // conv input bf16 [4096][1024]
  u16* zb     = (u16*)take(8388608);     // z bf16 [4096][1024]
  u16* dtb    = (u16*)take(8388608);     // dt bf16 (post-softplus) [4096][1024]
  u16* xdblp  = (u16*)take(6291456);     // split-K bf16 parts [8][4096][96]
  unsigned* PS= (unsigned*)take(8388608);// packed (P,S) bf16x2 [b][c=64][d][n]
  u16* SI     = (u16*)take(4194304);     // chunk init states bf16

  // converts (fused)
  k_cvt_all<<<7360, 256, 0, stream>>>(x, W_in, W_out, W_dt, W_x,
                                      xb, w1b, wob, wdtb, wxb);
  // GEMM1: x @ W_in^T -> bf16 xc / z halves, full-tile LDS-staged stores
  dim3 g1(16, 32, 1);
  k_gemm_bt<2><<<g1, 512, 0, stream>>>(xb, 1024, w1b, 1024, nullptr, 0, 2048,
                                       1024, 1024, 0, 4, nullptr, nullptr, xcb, zb);
  // conv + silu -> xs bf16
  k_conv2<<<512, 256, 0, stream>>>(xcb, convw, xsb);
  // GEMM2: x_dbl = xs @ W_x^T (deterministic split-K=8, bf16 parts)
  dim3 g2(1, 32, 8);
  k_gemm_bt<4><<<g2, 512, 0, stream>>>(xsb, 1024, wxb, 1024, nullptr, 96, 96,
                                       1024, 128, 393216, 0, nullptr, nullptr, xdblp, nullptr);
  k_red8<<<384, 256, 0, stream>>>(xdblp, xdblb);
  // dt GEMM (K=64) with fused softplus+bias -> bf16 dt
  dim3 g4(8, 32, 1);
  k_gemm_bt<3><<<g4, 512, 0, stream>>>(xdblb, 96, wdtb, 64, nullptr, 0, 1024,
                                       64, 64, 0, 3, b_dt, nullptr, dtb, nullptr);
  // chunked scan (L=32, NC=64), uniform-A fast path, LDS slab loads
  dim3 gs(4, 64, 2);
  k_scanA<<<gs, 256, 0, stream>>>(dtb, xsb, xdblb, A_log, PS);
  k_scanB<<<128, 256, 0, stream>>>(PS, SI);
  k_scanC<<<gs, 256, 0, stream>>>(dtb, xsb, xdblb, A_log, SI, W_C, D_par, yb);
  // GEMM3: out = (y @ W_out^T) * silu(z)  (z bf16)
  dim3 g3(8, 32, 1);
  k_gemm_bt<1><<<g3, 512, 0, stream>>>(yb, 1024, wob, 1024, out, 1024, 1024,
                                       1024, 1024, 0, 3, nullptr, zb, nullptr, nullptr);
}

// Round 13
// 111.507 us; speedup vs baseline: 1.1145x; 1.0668x over previous
//
#include <hip/hip_runtime.h>

typedef unsigned short u16;
typedef __attribute__((ext_vector_type(4))) float f4;
typedef __attribute__((ext_vector_type(4))) unsigned short us4;
typedef __attribute__((ext_vector_type(8))) unsigned short us8;
typedef __attribute__((ext_vector_type(8))) short s8v;
typedef __attribute__((ext_vector_type(4))) float f32x4;
typedef __attribute__((ext_vector_type(4))) unsigned int u4v;

#define DEVI __device__ __forceinline__

DEVI u16 f2bf(float f) {
  unsigned u = __float_as_uint(f);
  u = (u + 0x7FFFu + ((u >> 16) & 1u)) >> 16;
  return (u16)u;
}
DEVI float bf2f(u16 v) { return __uint_as_float(((unsigned)v) << 16); }
DEVI float siluf(float x) { return x / (1.f + __expf(-x)); }

// ---------------- fused converts (x, W_in, W_out, W_dt, W_x-padded) -------
__global__ void k_cvt_all(const float* __restrict__ x, const float* __restrict__ w1,
                          const float* __restrict__ wo, const float* __restrict__ wdt,
                          const float* __restrict__ wx,
                          u16* __restrict__ xb, u16* __restrict__ w1b,
                          u16* __restrict__ wob, u16* __restrict__ wdtb,
                          u16* __restrict__ wxb) {
  const int blk = blockIdx.x;
  const int tid = threadIdx.x;
  if (blk >= 7232) {  // W_x: 96x1024 -> 128x1024 zero-padded
    int i = (blk - 7232) * 256 + tid;
    int row = i >> 8;
    us4 o;
    if (row < 96) {
      f4 v = ((const f4*)wx)[i];
#pragma unroll
      for (int j = 0; j < 4; ++j) o[j] = f2bf(v[j]);
    } else {
      o[0] = 0; o[1] = 0; o[2] = 0; o[3] = 0;
    }
    ((us4*)wxb)[i] = o;
    return;
  }
  const float* src; u16* dst; int i;
  if (blk < 4096)      { src = x;   dst = xb;   i = blk * 256 + tid; }
  else if (blk < 6144) { src = w1;  dst = w1b;  i = (blk - 4096) * 256 + tid; }
  else if (blk < 7168) { src = wo;  dst = wob;  i = (blk - 6144) * 256 + tid; }
  else                 { src = wdt; dst = wdtb; i = (blk - 7168) * 256 + tid; }
  f4 v = ((const f4*)src)[i];
  us4 o;
#pragma unroll
  for (int j = 0; j < 4; ++j) o[j] = f2bf(v[j]);
  ((us4*)dst)[i] = o;
}

// ---------------- bf16 NT GEMM: BMx128 tile, BK=64, 8 waves (512 thr) ------
// BM=128: wave grid 2Mx4N, per-wave 64x32 (acc 4x2). LDS 32 KB.
// BM=64:  wave grid 2Mx4N, per-wave 32x32 (acc 2x2). LDS 24 KB. 2x grid occupancy.
// Wave A-row base = wr * (BM/2)  ->  aoff shift = MSH-1  (bug in R12 was MSH-2).
// EPI 0: fp32 store to C (+blockIdx.z*zstride for split-K parts)
// EPI 1: fp32 store to C, multiplied by silu(bf16 zsrc[rr*1024+cc])
// EPI 2: bf16 full-tile LDS-staged coalesced split store (BM=128 only)
// EPI 3: bf16 store of softplus(v + bvec[cc]) + 1e-5 -> ob1 (dt)
// EPI 4: bf16 store to ob1 (+blockIdx.z*zstride), ldc stride (split-K parts)
template <int EPI, int BM>
__global__ __launch_bounds__(512, 2)
void k_gemm_bt(const u16* __restrict__ A, int lda,
               const u16* __restrict__ B, int ldb,
               float* __restrict__ C, int ldc, int nvalid,
               int K, int kchunk, size_t zstride, int lognx,
               const float* __restrict__ bvec,
               const u16* __restrict__ zsrc,
               u16* __restrict__ ob1, u16* __restrict__ ob2) {
  constexpr int MSH = (BM == 128) ? 7 : 6;       // log2(BM)
  constexpr int MREP = BM / 32;                  // acc m-fragments per wave
  constexpr int APLANE = BM * 64;                // bytes per A K-plane
  __shared__ __align__(16) char smem[2 * APLANE + 16384];
  const int tid = threadIdx.x;
  const int wave = tid >> 6, lane = tid & 63;

  // XCD-aware bijective swizzle (nwg % 8 == 0 for all call sites)
  const int nwg = gridDim.x * gridDim.y;
  int bid = blockIdx.y * gridDim.x + blockIdx.x;
  {
    const int cpx = nwg >> 3;
    bid = (bid & 7) * cpx + (bid >> 3);
  }
  const int mBase = (bid >> lognx) << MSH;
  const int nBase = (bid & ((1 << lognx) - 1)) << 7;
  const int kbeg = blockIdx.z * kchunk;
  int kend = kbeg + kchunk; if (kend > K) kend = K;
  if (EPI == 4) ob1 += (size_t)blockIdx.z * zstride;
  else          C   += (size_t)blockIdx.z * zstride;

  const int wr = wave >> 2, wc = wave & 3;      // 2M x 4N wave grid

  // A staging mapping
  const u16* Ag;
  char* ldsA;
  if (BM == 128) {
    const int row0 = tid >> 2, kg = tid & 3;    // 128 rows x 4 k-groups, 2 gloads
    Ag = A + (size_t)(mBase + row0) * lda + kg * 8;
    ldsA = smem + wave * 1024;                  // plane0; plane1 at +APLANE
  } else {
    const int plane = tid >> 8;                 // waves 0-3: K 0..31, 4-7: K 32..63
    const int rtid = tid & 255;
    const int row0 = rtid >> 2, kg = rtid & 3;  // 64 rows x 4 k-groups, 1 gload
    Ag = A + (size_t)(mBase + row0) * lda + kg * 8 + plane * 32;
    ldsA = smem + (wave >> 2) * APLANE + (wave & 3) * 1024;
  }
  // B staging (always 128 rows x 2 planes)
  const int row0b = tid >> 2, kgb = tid & 3;
  const u16* Bg = B + (size_t)(nBase + row0b) * ldb + kgb * 8;
  char* ldsB0 = smem + 2 * APLANE + wave * 1024;
  char* ldsB1 = ldsB0 + 8192;

  const u16* As = (const u16*)smem;
  const u16* Bs = (const u16*)(smem + 2 * APLANE);

  const int fr = lane & 15, fk = (lane >> 4) << 3;
  const int aoff = ((wr << (MSH - 1)) + fr) * 32 + fk;  // wave rows: wr*(BM/2)
  const int boff = ((wc << 5) + fr) * 32 + fk;

  f32x4 acc[MREP][2];
#pragma unroll
  for (int m = 0; m < MREP; ++m)
#pragma unroll
    for (int n = 0; n < 2; ++n) acc[m][n] = {0.f, 0.f, 0.f, 0.f};

  for (int k0 = kbeg; k0 < kend; k0 += 64) {
    __syncthreads();
    if (BM == 128) {
      __builtin_amdgcn_global_load_lds((const __attribute__((address_space(1))) void*)(Ag + k0),
                                       (__attribute__((address_space(3))) void*)(ldsA), 16, 0, 0);
      __builtin_amdgcn_global_load_lds((const __attribute__((address_space(1))) void*)(Ag + k0 + 32),
                                       (__attribute__((address_space(3))) void*)(ldsA + APLANE), 16, 0, 0);
    } else {
      __builtin_amdgcn_global_load_lds((const __attribute__((address_space(1))) void*)(Ag + k0),
                                       (__attribute__((address_space(3))) void*)(ldsA), 16, 0, 0);
    }
    __builtin_amdgcn_global_load_lds((const __attribute__((address_space(1))) void*)(Bg + k0),
                                     (__attribute__((address_space(3))) void*)(ldsB0), 16, 0, 0);
    __builtin_amdgcn_global_load_lds((const __attribute__((address_space(1))) void*)(Bg + k0 + 32),
                                     (__attribute__((address_space(3))) void*)(ldsB1), 16, 0, 0);
    __syncthreads();
#pragma unroll
    for (int kk = 0; kk < 2; ++kk) {
      const u16* Ap = As + kk * (APLANE / 2);
      const u16* Bp = Bs + (kk << 12);
      s8v av[MREP], bv[2];
#pragma unroll
      for (int m = 0; m < MREP; ++m) av[m] = *(const s8v*)(Ap + aoff + (m << 9));
#pragma unroll
      for (int n = 0; n < 2; ++n) bv[n] = *(const s8v*)(Bp + boff + (n << 9));
#pragma unroll
      for (int m = 0; m < MREP; ++m)
#pragma unroll
        for (int n = 0; n < 2; ++n)
          acc[m][n] = __builtin_amdgcn_mfma_f32_16x16x32_bf16(av[m], bv[n], acc[m][n], 0, 0, 0);
    }
  }

  if constexpr (EPI == 2) {
    // full 128x128 bf16 tile staged once, then coalesced us8 stores (BM=128)
    u16* ct = (u16*)smem;
    const int r16 = (lane >> 4) << 2;
    __syncthreads();
#pragma unroll
    for (int m = 0; m < MREP; ++m)
#pragma unroll
      for (int n = 0; n < 2; ++n)
#pragma unroll
        for (int j = 0; j < 4; ++j)
          ct[((wr << 6) + (m << 4) + r16 + j) * 128 + (wc << 5) + (n << 4) + fr] =
              f2bf(acc[m][n][j]);
    __syncthreads();
    u16* dst = (nBase < 1024) ? ob1 : ob2;
    const int ncol = nBase & 1023;
#pragma unroll
    for (int it = 0; it < 4; ++it) {
      const int s = it * 512 + tid;         // 2048 us8 slots
      const int tr = s >> 4, colq = (s & 15) << 3;
      *(us8*)(dst + ((size_t)(mBase + tr) << 10) + ncol + colq) =
          *(const us8*)(ct + tr * 128 + colq);
    }
    return;
  }

  const int crow0 = mBase + (wr << (MSH - 1)) + ((lane >> 4) << 2);
  const int ccol0 = nBase + (wc << 5) + (lane & 15);
#pragma unroll
  for (int m = 0; m < MREP; ++m) {
#pragma unroll
    for (int n = 0; n < 2; ++n) {
      const int cc = ccol0 + (n << 4);
      if (cc < nvalid) {
#pragma unroll
        for (int j = 0; j < 4; ++j) {
          const int rr = crow0 + (m << 4) + j;
          float v = acc[m][n][j];
          if (EPI == 0) {
            C[(size_t)rr * ldc + cc] = v;
          } else if (EPI == 1) {
            v *= siluf(bf2f(zsrc[((size_t)rr << 10) + cc]));
            C[(size_t)rr * ldc + cc] = v;
          } else if (EPI == 3) {
            float pre = v + bvec[cc];
            float dtv = (pre > 20.f ? pre : __logf(1.f + __expf(pre))) + 1e-5f;
            ob1[((size_t)rr << 10) + cc] = f2bf(dtv);
          } else {  // EPI == 4
            ob1[(size_t)rr * ldc + cc] = f2bf(v);
          }
        }
      }
    }
  }
}

// ---------------- split-K reduce (8 bf16 parts) -> bf16 x_dbl ------------
__global__ void k_red8(const u16* __restrict__ parts, u16* __restrict__ xdblb) {
  const int i = blockIdx.x * 256 + threadIdx.x;  // us4 quads over 4096*96/4
  f4 s = {0.f, 0.f, 0.f, 0.f};
#pragma unroll
  for (int z = 0; z < 8; ++z) {
    us4 v = ((const us4*)(parts + (size_t)z * 393216))[i];
#pragma unroll
    for (int j = 0; j < 4; ++j) s[j] += bf2f(v[j]);
  }
  us4 o;
#pragma unroll
  for (int j = 0; j < 4; ++j) o[j] = f2bf(s[j]);
  ((us4*)xdblb)[i] = o;
}

// ---------------- conv(width3) + silu, rolling window, bf16 in/out -------
__global__ void k_conv2(const u16* __restrict__ xcb, const float* __restrict__ conv_w,
                        u16* __restrict__ xsb) {
  const int b = blockIdx.x >> 8;
  const int t0 = (blockIdx.x & 255) << 3;
  const int d = threadIdx.x << 2;
  const u16* base = xcb + ((size_t)b * 2048 << 10) + d;
  const f4* cw = (const f4*)(conv_w + d * 3);
  f4 c0 = cw[0], c1 = cw[1], c2 = cw[2];
  const float w[12] = {c0[0], c0[1], c0[2], c0[3], c1[0], c1[1], c1[2], c1[3],
                       c2[0], c2[1], c2[2], c2[3]};
  const f4 zero = {0.f, 0.f, 0.f, 0.f};
  auto ld = [&](int t) -> f4 {
    us4 v = *(const us4*)(base + ((size_t)t << 10));
    f4 r;
#pragma unroll
    for (int j = 0; j < 4; ++j) r[j] = bf2f(v[j]);
    return r;
  };
  f4 prev = (t0 == 0) ? zero : ld(t0 - 1);
  f4 cur = ld(t0);
#pragma unroll
  for (int i = 0; i < 8; ++i) {
    const int t = t0 + i;
    f4 nxt = (t == 2047) ? zero : ld(t + 1);
    us4 xbv;
#pragma unroll
    for (int j = 0; j < 4; ++j) {
      float xc = prev[j] * w[j * 3] + cur[j] * w[j * 3 + 1] + nxt[j] * w[j * 3 + 2];
      xbv[j] = f2bf(siluf(xc));
    }
    *(us4*)(xsb + ((size_t)(b * 2048 + t) << 10) + d) = xbv;
    prev = cur; cur = nxt;
  }
}

// ---------------- chunked scan: L=32, NC=64, layout [b][c][d][n] ----------
// pass A: per-chunk prod(A) and local end state, packed bf16x2 in u32.
__global__ void k_scanA(const u16* __restrict__ dtb, const u16* __restrict__ xsb,
                        const u16* __restrict__ xdblb, const float* __restrict__ A_log,
                        unsigned* __restrict__ PS) {
  __shared__ float bxs[32][16];
  __shared__ __align__(16) u16 dts[32][256];
  __shared__ __align__(16) u16 xss[32][256];
  const int tid = threadIdx.x;
  const int d0 = blockIdx.x << 8;
  const int d = d0 + tid;
  const int c = blockIdx.y;
  const int b = blockIdx.z;
  const int btBase = (b << 11) + (c << 5);
  {
    const u16* dtp = dtb + ((size_t)btBase << 10) + d0;
    const u16* xsp = xsb + ((size_t)btBase << 10) + d0;
#pragma unroll
    for (int k = 0; k < 4; ++k) {
      const int i = k * 256 + tid;
      const int row = i >> 5, c8 = (i & 31) << 3;
      *(us8*)&dts[row][c8] = *(const us8*)(dtp + ((size_t)row << 10) + c8);
      *(us8*)&xss[row][c8] = *(const us8*)(xsp + ((size_t)row << 10) + c8);
    }
  }
  for (int i = tid; i < 512; i += 256) {
    bxs[i >> 4][i & 15] = bf2f(xdblb[(size_t)(btBase + (i >> 4)) * 96 + 64 + (i & 15)]);
  }
  float a[16];
  {
    const f4* al = (const f4*)(A_log + d * 16);
#pragma unroll
    for (int q = 0; q < 4; ++q) {
      f4 v = al[q];
#pragma unroll
      for (int j = 0; j < 4; ++j) a[q * 4 + j] = -__expf(v[j]);
    }
  }
  bool uni = true;
#pragma unroll
  for (int n = 1; n < 16; ++n) uni = uni && (a[n] == a[0]);
  __syncthreads();
  float P[16], S[16];
#pragma unroll
  for (int n = 0; n < 16; ++n) { P[n] = 1.f; S[n] = 0.f; }
  if (uni) {
    const float a0 = a[0];
    float Pu = 1.f;
#pragma unroll
    for (int tau = 0; tau < 32; ++tau) {
      const float dt = bf2f(dts[tau][tid]);
      const float dx = dt * bf2f(xss[tau][tid]);
      const float Av = __expf(a0 * dt);
      Pu *= Av;
#pragma unroll
      for (int n = 0; n < 16; ++n) S[n] = fmaf(Av, S[n], bxs[tau][n] * dx);
    }
#pragma unroll
    for (int n = 0; n < 16; ++n) P[n] = Pu;
  } else {
#pragma unroll
    for (int tau = 0; tau < 32; ++tau) {
      const float dt = bf2f(dts[tau][tid]);
      const float dx = dt * bf2f(xss[tau][tid]);
#pragma unroll
      for (int n = 0; n < 16; ++n) {
        const float Av = __expf(a[n] * dt);
        P[n] *= Av;
        S[n] = fmaf(Av, S[n], bxs[tau][n] * dx);
      }
    }
  }
  const size_t base = (size_t)(((b << 6) + c) * 1024 + d) << 4;
#pragma unroll
  for (int q = 0; q < 4; ++q) {
    u4v pk;
#pragma unroll
    for (int j = 0; j < 4; ++j) {
      pk[j] = (unsigned)f2bf(P[q * 4 + j]) | ((unsigned)f2bf(S[q * 4 + j]) << 16);
    }
    *(u4v*)(PS + base + q * 4) = pk;
  }
}

// pass B: sequential combine of 64 chunk summaries -> chunk init states (bf16)
__global__ void k_scanB(const unsigned* __restrict__ PS, u16* __restrict__ SI) {
  const int i = (blockIdx.x << 8) + threadIdx.x;  // 32768
  const int n = i & 15;
  const int dd = (i >> 4) & 1023;
  const int b = i >> 14;
  float s = 0.f;
  for (int c = 0; c < 64; ++c) {
    const size_t idx = ((size_t)(((b << 6) + c) * 1024 + dd) << 4) + n;
    const unsigned w = PS[idx];
    SI[idx] = f2bf(s);
    s = fmaf(bf2f((u16)(w & 0xFFFF)), s, bf2f((u16)(w >> 16)));
  }
}

// pass C: replay chunk with known init state; emit y (bf16) via LDS slab
__global__ void k_scanC(const u16* __restrict__ dtb, const u16* __restrict__ xsb,
                        const u16* __restrict__ xdblb, const float* __restrict__ A_log,
                        const u16* __restrict__ SI, const float* __restrict__ W_C,
                        const float* __restrict__ D_param, u16* __restrict__ yb) {
  __shared__ float bxs[32][32];  // [tau][0:16)=B, [16:32)=C
  __shared__ __align__(16) u16 dts[32][256];
  __shared__ __align__(16) u16 xss[32][256];
  __shared__ __align__(16) u16 ys[32][256];
  const int tid = threadIdx.x;
  const int d0 = blockIdx.x << 8;
  const int d = d0 + tid;
  const int c = blockIdx.y;
  const int b = blockIdx.z;
  const int btBase = (b << 11) + (c << 5);
  {
    const u16* dtp = dtb + ((size_t)btBase << 10) + d0;
    const u16* xsp = xsb + ((size_t)btBase << 10) + d0;
#pragma unroll
    for (int k = 0; k < 4; ++k) {
      const int i = k * 256 + tid;
      const int row = i >> 5, c8 = (i & 31) << 3;
      *(us8*)&dts[row][c8] = *(const us8*)(dtp + ((size_t)row << 10) + c8);
      *(us8*)&xss[row][c8] = *(const us8*)(xsp + ((size_t)row << 10) + c8);
    }
  }
  for (int i = tid; i < 1024; i += 256) {
    bxs[i >> 5][i & 31] = bf2f(xdblb[(size_t)(btBase + (i >> 5)) * 96 + 64 + (i & 31)]);
  }
  float a[16], wc[16];
  {
    const f4* al = (const f4*)(A_log + d * 16);
    const f4* wcp = (const f4*)(W_C + d * 16);
#pragma unroll
    for (int q = 0; q < 4; ++q) {
      f4 v = al[q], u = wcp[q];
#pragma unroll
      for (int j = 0; j < 4; ++j) { a[q * 4 + j] = -__expf(v[j]); wc[q * 4 + j] = u[j]; }
    }
  }
  bool uni = true;
#pragma unroll
  for (int n = 1; n < 16; ++n) uni = uni && (a[n] == a[0]);
  const float Dp = D_param[d];
  float s[16];
  const size_t base = (size_t)(((b << 6) + c) * 1024 + d) << 4;
#pragma unroll
  for (int q = 0; q < 4; ++q) {
    us4 v = *(const us4*)(SI + base + q * 4);
#pragma unroll
    for (int j = 0; j < 4; ++j) s[q * 4 + j] = bf2f(v[j]);
  }
  __syncthreads();
  if (uni) {
    const float a0 = a[0];
#pragma unroll
    for (int tau = 0; tau < 32; ++tau) {
      const float dt = bf2f(dts[tau][tid]);
      const float xs = bf2f(xss[tau][tid]);
      const float dx = dt * xs;
      const float Av = __expf(a0 * dt);
      float ssum = 0.f, cp = 0.f;
#pragma unroll
      for (int n = 0; n < 16; ++n) {
        s[n] = fmaf(Av, s[n], bxs[tau][n] * dx);
        ssum += s[n];
        cp = fmaf(bxs[tau][16 + n], wc[n], cp);
      }
      ys[tau][tid] = f2bf(fmaf(cp, ssum, Dp * xs));
    }
  } else {
#pragma unroll
    for (int tau = 0; tau < 32; ++tau) {
      const float dt = bf2f(dts[tau][tid]);
      const float xs = bf2f(xss[tau][tid]);
      const float dx = dt * xs;
      float ssum = 0.f, cp = 0.f;
#pragma unroll
      for (int n = 0; n < 16; ++n) {
        const float Av = __expf(a[n] * dt);
        s[n] = fmaf(Av, s[n], bxs[tau][n] * dx);
        ssum += s[n];
        cp = fmaf(bxs[tau][16 + n], wc[n], cp);
      }
      ys[tau][tid] = f2bf(fmaf(cp, ssum, Dp * xs));
    }
  }
  __syncthreads();
  {
    u16* yp = yb + ((size_t)btBase << 10) + d0;
#pragma unroll
    for (int k = 0; k < 4; ++k) {
      const int i = k * 256 + tid;
      const int row = i >> 5, c8 = (i & 31) << 3;
      *(us8*)(yp + ((size_t)row << 10) + c8) = *(const us8*)&ys[row][c8];
    }
  }
}

extern "C" void kernel_launch(void* const* d_in, const int* in_sizes, int n_in,
                              void* d_out, int out_size, void* d_ws, size_t ws_size,
                              hipStream_t stream) {
  const float* x     = (const float*)d_in[0];
  const float* W_in  = (const float*)d_in[1];
  const float* convw = (const float*)d_in[2];
  const float* W_x   = (const float*)d_in[3];
  const float* W_dt  = (const float*)d_in[4];
  const float* b_dt  = (const float*)d_in[5];
  const float* A_log = (const float*)d_in[6];
  const float* D_par = (const float*)d_in[7];
  const float* W_C   = (const float*)d_in[8];
  const float* W_out = (const float*)d_in[9];
  float* out = (float*)d_out;
  (void)in_sizes; (void)n_in; (void)out_size; (void)ws_size;

  char* w = (char*)d_ws;
  auto take = [&](size_t bytes) { char* p = w; w += (bytes + 255) & ~(size_t)255; return p; };
  u16* xb     = (u16*)take(8388608);     // x bf16 [4096][1024]
  u16* w1b    = (u16*)take(4194304);     // W_in bf16 [2048][1024]
  u16* wxb    = (u16*)take(262144);      // W_x bf16 padded [128][1024]
  u16* wob    = (u16*)take(2097152);     // W_out bf16 [1024][1024]
  u16* wdtb   = (u16*)take(131072);      // W_dt bf16 [1024][64]
  u16* xdblb  = (u16*)take(786432);      // x_dbl bf16 [4096][96]
  u16* yb     = (u16*)take(8388608);     // y bf16 [4096][1024]
  u16* xsb    = (u16*)take(8388608);     // xs bf16 [4096][1024]
  u16* xcb    = (u16*)take(8388608);     // xc bf16 [4096][1024]
  u16* zb     = (u16*)take(8388608);     // z bf16 [4096][1024]
  u16* dtb    = (u16*)take(8388608);     // dt bf16 (post-softplus) [4096][1024]
  u16* xdblp  = (u16*)take(6291456);     // split-K bf16 parts [8][4096][96]
  unsigned* PS= (unsigned*)take(8388608);// packed (P,S) bf16x2 [b][c=64][d][n]
  u16* SI     = (u16*)take(4194304);     // chunk init states bf16

  // converts (fused)
  k_cvt_all<<<7360, 256, 0, stream>>>(x, W_in, W_out, W_dt, W_x,
                                      xb, w1b, wob, wdtb, wxb);
  // GEMM1: x @ W_in^T -> bf16 xc / z halves, full-tile LDS-staged stores
  dim3 g1(16, 32, 1);
  k_gemm_bt<2, 128><<<g1, 512, 0, stream>>>(xb, 1024, w1b, 1024, nullptr, 0, 2048,
                                            1024, 1024, 0, 4, nullptr, nullptr, xcb, zb);
  // conv + silu -> xs bf16
  k_conv2<<<512, 256, 0, stream>>>(xcb, convw, xsb);
  // GEMM2: x_dbl = xs @ W_x^T (split-K=8, bf16 parts, BM=64 -> 512 blocks)
  dim3 g2(1, 64, 8);
  k_gemm_bt<4, 64><<<g2, 512, 0, stream>>>(xsb, 1024, wxb, 1024, nullptr, 96, 96,
                                           1024, 128, 393216, 0, nullptr, nullptr, xdblp, nullptr);
  k_red8<<<384, 256, 0, stream>>>(xdblp, xdblb);
  // dt GEMM (K=64) fused softplus+bias -> bf16 dt (BM=64 -> 512 blocks)
  dim3 g4(8, 64, 1);
  k_gemm_bt<3, 64><<<g4, 512, 0, stream>>>(xdblb, 96, wdtb, 64, nullptr, 0, 1024,
                                           64, 64, 0, 3, b_dt, nullptr, dtb, nullptr);
  // chunked scan (L=32, NC=64), uniform-A fast path, LDS slab loads
  dim3 gs(4, 64, 2);
  k_scanA<<<gs, 256, 0, stream>>>(dtb, xsb, xdblb, A_log, PS);
  k_scanB<<<128, 256, 0, stream>>>(PS, SI);
  k_scanC<<<gs, 256, 0, stream>>>(dtb, xsb, xdblb, A_log, SI, W_C, D_par, yb);
  // GEMM3: out = (y @ W_out^T) * silu(z)  (BM=64 -> 512 blocks)
  dim3 g3(8, 64, 1);
  k_gemm_bt<1, 64><<<g3, 512, 0, stream>>>(yb, 1024, wob, 1024, out, 1024, 1024,
                                           1024, 1024, 0, 3, nullptr, zb, nullptr, nullptr);
}

// Round 14
// 108.254 us; speedup vs baseline: 1.1480x; 1.0301x over previous
//
#include <hip/hip_runtime.h>

typedef unsigned short u16;
typedef __attribute__((ext_vector_type(4))) float f4;
typedef __attribute__((ext_vector_type(4))) unsigned short us4;
typedef __attribute__((ext_vector_type(8))) unsigned short us8;
typedef __attribute__((ext_vector_type(8))) short s8v;
typedef __attribute__((ext_vector_type(4))) float f32x4;
typedef __attribute__((ext_vector_type(4))) unsigned int u4v;

#define DEVI __device__ __forceinline__

DEVI u16 f2bf(float f) {
  unsigned u = __float_as_uint(f);
  u = (u + 0x7FFFu + ((u >> 16) & 1u)) >> 16;
  return (u16)u;
}
DEVI float bf2f(u16 v) { return __uint_as_float(((unsigned)v) << 16); }
DEVI float siluf(float x) { return x / (1.f + __expf(-x)); }

// ---------------- fused converts (x, W_in, W_out, W_dt, W_x-padded) -------
__global__ void k_cvt_all(const float* __restrict__ x, const float* __restrict__ w1,
                          const float* __restrict__ wo, const float* __restrict__ wdt,
                          const float* __restrict__ wx,
                          u16* __restrict__ xb, u16* __restrict__ w1b,
                          u16* __restrict__ wob, u16* __restrict__ wdtb,
                          u16* __restrict__ wxb) {
  const int blk = blockIdx.x;
  const int tid = threadIdx.x;
  if (blk >= 7232) {  // W_x: 96x1024 -> 128x1024 zero-padded
    int i = (blk - 7232) * 256 + tid;
    int row = i >> 8;
    us4 o;
    if (row < 96) {
      f4 v = ((const f4*)wx)[i];
#pragma unroll
      for (int j = 0; j < 4; ++j) o[j] = f2bf(v[j]);
    } else {
      o[0] = 0; o[1] = 0; o[2] = 0; o[3] = 0;
    }
    ((us4*)wxb)[i] = o;
    return;
  }
  const float* src; u16* dst; int i;
  if (blk < 4096)      { src = x;   dst = xb;   i = blk * 256 + tid; }
  else if (blk < 6144) { src = w1;  dst = w1b;  i = (blk - 4096) * 256 + tid; }
  else if (blk < 7168) { src = wo;  dst = wob;  i = (blk - 6144) * 256 + tid; }
  else                 { src = wdt; dst = wdtb; i = (blk - 7168) * 256 + tid; }
  f4 v = ((const f4*)src)[i];
  us4 o;
#pragma unroll
  for (int j = 0; j < 4; ++j) o[j] = f2bf(v[j]);
  ((us4*)dst)[i] = o;
}

// ---------------- bf16 NT GEMM: BMx128 tile, BK-deep K-step, 8 waves ------
// BM=128: wave grid 2Mx4N, per-wave 64x32 (acc 4x2).
// BM=64:  wave grid 2Mx4N, per-wave 32x32 (acc 2x2). 2x grid occupancy.
// BK planes of [BM][32]; LDS = BK/32*(BM+128)*64 bytes.
//   BM=128,BK=128: 64 KB (2 blocks/CU). BM=64,BK=128: 48 KB. BM=64,BK=64: 24 KB.
// K-plane accumulation order identical across BK choices (bit-identical C).
// EPI 0: fp32 store to C (+blockIdx.z*zstride for split-K parts)
// EPI 1: fp32 store to C, multiplied by silu(bf16 zsrc[rr*1024+cc])
// EPI 2: bf16 full-tile LDS-staged coalesced split store (BM=128 only)
// EPI 3: bf16 store of softplus(v + bvec[cc]) + 1e-5 -> ob1 (dt)
// EPI 4: bf16 store to ob1 (+blockIdx.z*zstride), ldc stride (split-K parts)
template <int EPI, int BM, int BK>
__global__ __launch_bounds__(512, 2)
void k_gemm_bt(const u16* __restrict__ A, int lda,
               const u16* __restrict__ B, int ldb,
               float* __restrict__ C, int ldc, int nvalid,
               int K, int kchunk, size_t zstride, int lognx,
               const float* __restrict__ bvec,
               const u16* __restrict__ zsrc,
               u16* __restrict__ ob1, u16* __restrict__ ob2) {
  constexpr int MSH = (BM == 128) ? 7 : 6;       // log2(BM)
  constexpr int MREP = BM / 32;                  // acc m-fragments per wave
  constexpr int NPLANES = BK / 32;               // K-planes per K-step
  constexpr int APLANE_B = BM * 64;              // bytes per A plane
  constexpr int APLANE_U16 = BM * 32;            // u16 per A plane
  constexpr int SMEM_SZ = NPLANES * (APLANE_B + 8192);
  __shared__ __align__(16) char smem[SMEM_SZ];
  char* smemB = smem + NPLANES * APLANE_B;
  const int tid = threadIdx.x;
  const int wave = tid >> 6, lane = tid & 63;

  // XCD-aware bijective swizzle (nwg % 8 == 0 for all call sites)
  const int nwg = gridDim.x * gridDim.y;
  int bid = blockIdx.y * gridDim.x + blockIdx.x;
  {
    const int cpx = nwg >> 3;
    bid = (bid & 7) * cpx + (bid >> 3);
  }
  const int mBase = (bid >> lognx) << MSH;
  const int nBase = (bid & ((1 << lognx) - 1)) << 7;
  const int kbeg = blockIdx.z * kchunk;
  int kend = kbeg + kchunk; if (kend > K) kend = K;
  if (EPI == 4) ob1 += (size_t)blockIdx.z * zstride;
  else          C   += (size_t)blockIdx.z * zstride;

  const int wr = wave >> 2, wc = wave & 3;      // 2M x 4N wave grid

  // A source address (per-thread); LDS dest is linear tid*16 within each gload
  const u16* Ag;
  if (BM == 128) {
    Ag = A + (size_t)(mBase + (tid >> 2)) * lda + (tid & 3) * 8;
  } else {
    // 512 threads span 2 planes per gload: lanes 0-255 plane0, 256-511 plane1
    Ag = A + (size_t)(mBase + ((tid & 255) >> 2)) * lda + (tid & 3) * 8 + (tid >> 8) * 32;
  }
  const u16* Bg = B + (size_t)(nBase + (tid >> 2)) * ldb + (tid & 3) * 8;

  const u16* As = (const u16*)smem;
  const u16* Bs = (const u16*)smemB;

  const int fr = lane & 15, fk = (lane >> 4) << 3;
  const int aoff = ((wr << (MSH - 1)) + fr) * 32 + fk;  // wave rows: wr*(BM/2)
  const int boff = ((wc << 5) + fr) * 32 + fk;

  f32x4 acc[MREP][2];
#pragma unroll
  for (int m = 0; m < MREP; ++m)
#pragma unroll
    for (int n = 0; n < 2; ++n) acc[m][n] = {0.f, 0.f, 0.f, 0.f};

  for (int k0 = kbeg; k0 < kend; k0 += BK) {
    __syncthreads();
    if (BM == 128) {
#pragma unroll
      for (int g = 0; g < NPLANES; ++g)
        __builtin_amdgcn_global_load_lds(
            (const __attribute__((address_space(1))) void*)(Ag + k0 + g * 32),
            (__attribute__((address_space(3))) void*)(smem + g * APLANE_B + wave * 1024),
            16, 0, 0);
    } else {
#pragma unroll
      for (int h = 0; h < BK / 64; ++h)
        __builtin_amdgcn_global_load_lds(
            (const __attribute__((address_space(1))) void*)(Ag + k0 + h * 64),
            (__attribute__((address_space(3))) void*)(smem + h * 8192 + wave * 1024),
            16, 0, 0);
    }
#pragma unroll
    for (int g = 0; g < NPLANES; ++g)
      __builtin_amdgcn_global_load_lds(
          (const __attribute__((address_space(1))) void*)(Bg + k0 + g * 32),
          (__attribute__((address_space(3))) void*)(smemB + g * 8192 + wave * 1024),
          16, 0, 0);
    __syncthreads();
#pragma unroll
    for (int kk = 0; kk < NPLANES; ++kk) {
      const u16* Ap = As + kk * APLANE_U16;
      const u16* Bp = Bs + (kk << 12);
      s8v av[MREP], bv[2];
#pragma unroll
      for (int m = 0; m < MREP; ++m) av[m] = *(const s8v*)(Ap + aoff + (m << 9));
#pragma unroll
      for (int n = 0; n < 2; ++n) bv[n] = *(const s8v*)(Bp + boff + (n << 9));
#pragma unroll
      for (int m = 0; m < MREP; ++m)
#pragma unroll
        for (int n = 0; n < 2; ++n)
          acc[m][n] = __builtin_amdgcn_mfma_f32_16x16x32_bf16(av[m], bv[n], acc[m][n], 0, 0, 0);
    }
  }

  if constexpr (EPI == 2) {
    // full 128x128 bf16 tile staged once, then coalesced us8 stores (BM=128)
    u16* ct = (u16*)smem;
    const int r16 = (lane >> 4) << 2;
    __syncthreads();
#pragma unroll
    for (int m = 0; m < MREP; ++m)
#pragma unroll
      for (int n = 0; n < 2; ++n)
#pragma unroll
        for (int j = 0; j < 4; ++j)
          ct[((wr << 6) + (m << 4) + r16 + j) * 128 + (wc << 5) + (n << 4) + fr] =
              f2bf(acc[m][n][j]);
    __syncthreads();
    u16* dst = (nBase < 1024) ? ob1 : ob2;
    const int ncol = nBase & 1023;
#pragma unroll
    for (int it = 0; it < 4; ++it) {
      const int s = it * 512 + tid;         // 2048 us8 slots
      const int tr = s >> 4, colq = (s & 15) << 3;
      *(us8*)(dst + ((size_t)(mBase + tr) << 10) + ncol + colq) =
          *(const us8*)(ct + tr * 128 + colq);
    }
    return;
  }

  const int crow0 = mBase + (wr << (MSH - 1)) + ((lane >> 4) << 2);
  const int ccol0 = nBase + (wc << 5) + (lane & 15);
#pragma unroll
  for (int m = 0; m < MREP; ++m) {
#pragma unroll
    for (int n = 0; n < 2; ++n) {
      const int cc = ccol0 + (n << 4);
      if (cc < nvalid) {
#pragma unroll
        for (int j = 0; j < 4; ++j) {
          const int rr = crow0 + (m << 4) + j;
          float v = acc[m][n][j];
          if (EPI == 0) {
            C[(size_t)rr * ldc + cc] = v;
          } else if (EPI == 1) {
            v *= siluf(bf2f(zsrc[((size_t)rr << 10) + cc]));
            C[(size_t)rr * ldc + cc] = v;
          } else if (EPI == 3) {
            float pre = v + bvec[cc];
            float dtv = (pre > 20.f ? pre : __logf(1.f + __expf(pre))) + 1e-5f;
            ob1[((size_t)rr << 10) + cc] = f2bf(dtv);
          } else {  // EPI == 4
            ob1[(size_t)rr * ldc + cc] = f2bf(v);
          }
        }
      }
    }
  }
}

// ---------------- split-K reduce (8 bf16 parts) -> bf16 x_dbl ------------
__global__ void k_red8(const u16* __restrict__ parts, u16* __restrict__ xdblb) {
  const int i = blockIdx.x * 256 + threadIdx.x;  // us4 quads over 4096*96/4
  f4 s = {0.f, 0.f, 0.f, 0.f};
#pragma unroll
  for (int z = 0; z < 8; ++z) {
    us4 v = ((const us4*)(parts + (size_t)z * 393216))[i];
#pragma unroll
    for (int j = 0; j < 4; ++j) s[j] += bf2f(v[j]);
  }
  us4 o;
#pragma unroll
  for (int j = 0; j < 4; ++j) o[j] = f2bf(s[j]);
  ((us4*)xdblb)[i] = o;
}

// ---------------- conv(width3) + silu, rolling window, bf16 in/out -------
__global__ void k_conv2(const u16* __restrict__ xcb, const float* __restrict__ conv_w,
                        u16* __restrict__ xsb) {
  const int b = blockIdx.x >> 8;
  const int t0 = (blockIdx.x & 255) << 3;
  const int d = threadIdx.x << 2;
  const u16* base = xcb + ((size_t)b * 2048 << 10) + d;
  const f4* cw = (const f4*)(conv_w + d * 3);
  f4 c0 = cw[0], c1 = cw[1], c2 = cw[2];
  const float w[12] = {c0[0], c0[1], c0[2], c0[3], c1[0], c1[1], c1[2], c1[3],
                       c2[0], c2[1], c2[2], c2[3]};
  const f4 zero = {0.f, 0.f, 0.f, 0.f};
  auto ld = [&](int t) -> f4 {
    us4 v = *(const us4*)(base + ((size_t)t << 10));
    f4 r;
#pragma unroll
    for (int j = 0; j < 4; ++j) r[j] = bf2f(v[j]);
    return r;
  };
  f4 prev = (t0 == 0) ? zero : ld(t0 - 1);
  f4 cur = ld(t0);
#pragma unroll
  for (int i = 0; i < 8; ++i) {
    const int t = t0 + i;
    f4 nxt = (t == 2047) ? zero : ld(t + 1);
    us4 xbv;
#pragma unroll
    for (int j = 0; j < 4; ++j) {
      float xc = prev[j] * w[j * 3] + cur[j] * w[j * 3 + 1] + nxt[j] * w[j * 3 + 2];
      xbv[j] = f2bf(siluf(xc));
    }
    *(us4*)(xsb + ((size_t)(b * 2048 + t) << 10) + d) = xbv;
    prev = cur; cur = nxt;
  }
}

// ---------------- chunked scan: L=32, NC=64, layout [b][c][d][n] ----------
// pass A: per-chunk prod(A) and local end state, packed bf16x2 in u32.
__global__ void k_scanA(const u16* __restrict__ dtb, const u16* __restrict__ xsb,
                        const u16* __restrict__ xdblb, const float* __restrict__ A_log,
                        unsigned* __restrict__ PS) {
  __shared__ float bxs[32][16];
  __shared__ __align__(16) u16 dts[32][256];
  __shared__ __align__(16) u16 xss[32][256];
  const int tid = threadIdx.x;
  const int d0 = blockIdx.x << 8;
  const int d = d0 + tid;
  const int c = blockIdx.y;
  const int b = blockIdx.z;
  const int btBase = (b << 11) + (c << 5);
  {
    const u16* dtp = dtb + ((size_t)btBase << 10) + d0;
    const u16* xsp = xsb + ((size_t)btBase << 10) + d0;
#pragma unroll
    for (int k = 0; k < 4; ++k) {
      const int i = k * 256 + tid;
      const int row = i >> 5, c8 = (i & 31) << 3;
      *(us8*)&dts[row][c8] = *(const us8*)(dtp + ((size_t)row << 10) + c8);
      *(us8*)&xss[row][c8] = *(const us8*)(xsp + ((size_t)row << 10) + c8);
    }
  }
  for (int i = tid; i < 512; i += 256) {
    bxs[i >> 4][i & 15] = bf2f(xdblb[(size_t)(btBase + (i >> 4)) * 96 + 64 + (i & 15)]);
  }
  float a[16];
  {
    const f4* al = (const f4*)(A_log + d * 16);
#pragma unroll
    for (int q = 0; q < 4; ++q) {
      f4 v = al[q];
#pragma unroll
      for (int j = 0; j < 4; ++j) a[q * 4 + j] = -__expf(v[j]);
    }
  }
  bool uni = true;
#pragma unroll
  for (int n = 1; n < 16; ++n) uni = uni && (a[n] == a[0]);
  __syncthreads();
  float P[16], S[16];
#pragma unroll
  for (int n = 0; n < 16; ++n) { P[n] = 1.f; S[n] = 0.f; }
  if (uni) {
    const float a0 = a[0];
    float Pu = 1.f;
#pragma unroll
    for (int tau = 0; tau < 32; ++tau) {
      const float dt = bf2f(dts[tau][tid]);
      const float dx = dt * bf2f(xss[tau][tid]);
      const float Av = __expf(a0 * dt);
      Pu *= Av;
#pragma unroll
      for (int n = 0; n < 16; ++n) S[n] = fmaf(Av, S[n], bxs[tau][n] * dx);
    }
#pragma unroll
    for (int n = 0; n < 16; ++n) P[n] = Pu;
  } else {
#pragma unroll
    for (int tau = 0; tau < 32; ++tau) {
      const float dt = bf2f(dts[tau][tid]);
      const float dx = dt * bf2f(xss[tau][tid]);
#pragma unroll
      for (int n = 0; n < 16; ++n) {
        const float Av = __expf(a[n] * dt);
        P[n] *= Av;
        S[n] = fmaf(Av, S[n], bxs[tau][n] * dx);
      }
    }
  }
  const size_t base = (size_t)(((b << 6) + c) * 1024 + d) << 4;
#pragma unroll
  for (int q = 0; q < 4; ++q) {
    u4v pk;
#pragma unroll
    for (int j = 0; j < 4; ++j) {
      pk[j] = (unsigned)f2bf(P[q * 4 + j]) | ((unsigned)f2bf(S[q * 4 + j]) << 16);
    }
    *(u4v*)(PS + base + q * 4) = pk;
  }
}

// pass B: sequential combine of 64 chunk summaries -> chunk init states (bf16)
__global__ void k_scanB(const unsigned* __restrict__ PS, u16* __restrict__ SI) {
  const int i = (blockIdx.x << 8) + threadIdx.x;  // 32768
  const int n = i & 15;
  const int dd = (i >> 4) & 1023;
  const int b = i >> 14;
  float s = 0.f;
  for (int c = 0; c < 64; ++c) {
    const size_t idx = ((size_t)(((b << 6) + c) * 1024 + dd) << 4) + n;
    const unsigned w = PS[idx];
    SI[idx] = f2bf(s);
    s = fmaf(bf2f((u16)(w & 0xFFFF)), s, bf2f((u16)(w >> 16)));
  }
}

// pass C: replay chunk with known init state; emit y (bf16) via LDS slab
__global__ void k_scanC(const u16* __restrict__ dtb, const u16* __restrict__ xsb,
                        const u16* __restrict__ xdblb, const float* __restrict__ A_log,
                        const u16* __restrict__ SI, const float* __restrict__ W_C,
                        const float* __restrict__ D_param, u16* __restrict__ yb) {
  __shared__ float bxs[32][32];  // [tau][0:16)=B, [16:32)=C
  __shared__ __align__(16) u16 dts[32][256];
  __shared__ __align__(16) u16 xss[32][256];
  __shared__ __align__(16) u16 ys[32][256];
  const int tid = threadIdx.x;
  const int d0 = blockIdx.x << 8;
  const int d = d0 + tid;
  const int c = blockIdx.y;
  const int b = blockIdx.z;
  const int btBase = (b << 11) + (c << 5);
  {
    const u16* dtp = dtb + ((size_t)btBase << 10) + d0;
    const u16* xsp = xsb + ((size_t)btBase << 10) + d0;
#pragma unroll
    for (int k = 0; k < 4; ++k) {
      const int i = k * 256 + tid;
      const int row = i >> 5, c8 = (i & 31) << 3;
      *(us8*)&dts[row][c8] = *(const us8*)(dtp + ((size_t)row << 10) + c8);
      *(us8*)&xss[row][c8] = *(const us8*)(xsp + ((size_t)row << 10) + c8);
    }
  }
  for (int i = tid; i < 1024; i += 256) {
    bxs[i >> 5][i & 31] = bf2f(xdblb[(size_t)(btBase + (i >> 5)) * 96 + 64 + (i & 31)]);
  }
  float a[16], wc[16];
  {
    const f4* al = (const f4*)(A_log + d * 16);
    const f4* wcp = (const f4*)(W_C + d * 16);
#pragma unroll
    for (int q = 0; q < 4; ++q) {
      f4 v = al[q], u = wcp[q];
#pragma unroll
      for (int j = 0; j < 4; ++j) { a[q * 4 + j] = -__expf(v[j]); wc[q * 4 + j] = u[j]; }
    }
  }
  bool uni = true;
#pragma unroll
  for (int n = 1; n < 16; ++n) uni = uni && (a[n] == a[0]);
  const float Dp = D_param[d];
  float s[16];
  const size_t base = (size_t)(((b << 6) + c) * 1024 + d) << 4;
#pragma unroll
  for (int q = 0; q < 4; ++q) {
    us4 v = *(const us4*)(SI + base + q * 4);
#pragma unroll
    for (int j = 0; j < 4; ++j) s[q * 4 + j] = bf2f(v[j]);
  }
  __syncthreads();
  if (uni) {
    const float a0 = a[0];
#pragma unroll
    for (int tau = 0; tau < 32; ++tau) {
      const float dt = bf2f(dts[tau][tid]);
      const float xs = bf2f(xss[tau][tid]);
      const float dx = dt * xs;
      const float Av = __expf(a0 * dt);
      float ssum = 0.f, cp = 0.f;
#pragma unroll
      for (int n = 0; n < 16; ++n) {
        s[n] = fmaf(Av, s[n], bxs[tau][n] * dx);
        ssum += s[n];
        cp = fmaf(bxs[tau][16 + n], wc[n], cp);
      }
      ys[tau][tid] = f2bf(fmaf(cp, ssum, Dp * xs));
    }
  } else {
#pragma unroll
    for (int tau = 0; tau < 32; ++tau) {
      const float dt = bf2f(dts[tau][tid]);
      const float xs = bf2f(xss[tau][tid]);
      const float dx = dt * xs;
      float ssum = 0.f, cp = 0.f;
#pragma unroll
      for (int n = 0; n < 16; ++n) {
        const float Av = __expf(a[n] * dt);
        s[n] = fmaf(Av, s[n], bxs[tau][n] * dx);
        ssum += s[n];
        cp = fmaf(bxs[tau][16 + n], wc[n], cp);
      }
      ys[tau][tid] = f2bf(fmaf(cp, ssum, Dp * xs));
    }
  }
  __syncthreads();
  {
    u16* yp = yb + ((size_t)btBase << 10) + d0;
#pragma unroll
    for (int k = 0; k < 4; ++k) {
      const int i = k * 256 + tid;
      const int row = i >> 5, c8 = (i & 31) << 3;
      *(us8*)(yp + ((size_t)row << 10) + c8) = *(const us8*)&ys[row][c8];
    }
  }
}

extern "C" void kernel_launch(void* const* d_in, const int* in_sizes, int n_in,
                              void* d_out, int out_size, void* d_ws, size_t ws_size,
                              hipStream_t stream) {
  const float* x     = (const float*)d_in[0];
  const float* W_in  = (const float*)d_in[1];
  const float* convw = (const float*)d_in[2];
  const float* W_x   = (const float*)d_in[3];
  const float* W_dt  = (const float*)d_in[4];
  const float* b_dt  = (const float*)d_in[5];
  const float* A_log = (const float*)d_in[6];
  const float* D_par = (const float*)d_in[7];
  const float* W_C   = (const float*)d_in[8];
  const float* W_out = (const float*)d_in[9];
  float* out = (float*)d_out;
  (void)in_sizes; (void)n_in; (void)out_size; (void)ws_size;

  char* w = (char*)d_ws;
  auto take = [&](size_t bytes) { char* p = w; w += (bytes + 255) & ~(size_t)255; return p; };
  u16* xb     = (u16*)take(8388608);     // x bf16 [4096][1024]
  u16* w1b    = (u16*)take(4194304);     // W_in bf16 [2048][1024]
  u16* wxb    = (u16*)take(262144);      // W_x bf16 padded [128][1024]
  u16* wob    = (u16*)take(2097152);     // W_out bf16 [1024][1024]
  u16* wdtb   = (u16*)take(131072);      // W_dt bf16 [1024][64]
  u16* xdblb  = (u16*)take(786432);      // x_dbl bf16 [4096][96]
  u16* yb     = (u16*)take(8388608);     // y bf16 [4096][1024]
  u16* xsb    = (u16*)take(8388608);     // xs bf16 [4096][1024]
  u16* xcb    = (u16*)take(8388608);     // xc bf16 [4096][1024]
  u16* zb     = (u16*)take(8388608);     // z bf16 [4096][1024]
  u16* dtb    = (u16*)take(8388608);     // dt bf16 (post-softplus) [4096][1024]
  u16* xdblp  = (u16*)take(6291456);     // split-K bf16 parts [8][4096][96]
  unsigned* PS= (unsigned*)take(8388608);// packed (P,S) bf16x2 [b][c=64][d][n]
  u16* SI     = (u16*)take(4194304);     // chunk init states bf16

  // converts (fused)
  k_cvt_all<<<7360, 256, 0, stream>>>(x, W_in, W_out, W_dt, W_x,
                                      xb, w1b, wob, wdtb, wxb);
  // GEMM1: x @ W_in^T -> bf16 xc / z halves (BM=128, BK=128)
  dim3 g1(16, 32, 1);
  k_gemm_bt<2, 128, 128><<<g1, 512, 0, stream>>>(xb, 1024, w1b, 1024, nullptr, 0, 2048,
                                                 1024, 1024, 0, 4, nullptr, nullptr, xcb, zb);
  // conv + silu -> xs bf16
  k_conv2<<<512, 256, 0, stream>>>(xcb, convw, xsb);
  // GEMM2: x_dbl = xs @ W_x^T (split-K=8, bf16 parts, BM=64, BK=128)
  dim3 g2(1, 64, 8);
  k_gemm_bt<4, 64, 128><<<g2, 512, 0, stream>>>(xsb, 1024, wxb, 1024, nullptr, 96, 96,
                                                1024, 128, 393216, 0, nullptr, nullptr, xdblp, nullptr);
  k_red8<<<384, 256, 0, stream>>>(xdblp, xdblb);
  // dt GEMM (K=64) fused softplus+bias -> bf16 dt (BM=64, BK=64)
  dim3 g4(8, 64, 1);
  k_gemm_bt<3, 64, 64><<<g4, 512, 0, stream>>>(xdblb, 96, wdtb, 64, nullptr, 0, 1024,
                                               64, 64, 0, 3, b_dt, nullptr, dtb, nullptr);
  // chunked scan (L=32, NC=64), uniform-A fast path, LDS slab loads
  dim3 gs(4, 64, 2);
  k_scanA<<<gs, 256, 0, stream>>>(dtb, xsb, xdblb, A_log, PS);
  k_scanB<<<128, 256, 0, stream>>>(PS, SI);
  k_scanC<<<gs, 256, 0, stream>>>(dtb, xsb, xdblb, A_log, SI, W_C, D_par, yb);
  // GEMM3: out = (y @ W_out^T) * silu(z)  (BM=64, BK=128)
  dim3 g3(8, 64, 1);
  k_gemm_bt<1, 64, 128><<<g3, 512, 0, stream>>>(yb, 1024, wob, 1024, out, 1024, 1024,
                                                1024, 1024, 0, 3, nullptr, zb, nullptr, nullptr);
}